// Round 2
// baseline (2016.124 us; speedup 1.0000x reference)
//
#include <hip/hip_runtime.h>
#include <hip/hip_bf16.h>

using bf16 = __hip_bfloat16;

namespace {

constexpr int B_  = 1024;
constexpr int Sd  = 100;
constexpr int BS_ = B_ * Sd;

__device__ __forceinline__ float bfr(unsigned short u) {
  unsigned int x = ((unsigned int)u) << 16;
  float f;
  __builtin_memcpy(&f, &x, 4);
  return f;
}
__device__ __forceinline__ float b2f(bf16 x) { return __bfloat162float(x); }
__device__ __forceinline__ bf16  f2b(float x) { return __float2bfloat16(x); }

__device__ __forceinline__ float wsum(float v) {
#pragma unroll
  for (int m = 32; m > 0; m >>= 1) v += __shfl_xor(v, m);
  return v;
}
__device__ __forceinline__ float wmax(float v) {
#pragma unroll
  for (int m = 32; m > 0; m >>= 1) v = fmaxf(v, __shfl_xor(v, m));
  return v;
}
__device__ __forceinline__ float sum16(float v) {
#pragma unroll
  for (int m = 1; m < 16; m <<= 1) v += __shfl_xor(v, m);
  return v;
}

// ---------------------------------------------------------------------------
// In-LDS projection GEMM: dst = A[100][KD] @ Wp[KD][NC] + bias.
// Row-major dst (dst[r*dpitch + dbase + c]) or transposed (dst[(dbase+c)*dpitch + r]).
// ---------------------------------------------------------------------------
template <int KD, int NC>
__device__ __forceinline__ void proj_gemm(
    const bf16* __restrict__ A, const bf16* __restrict__ Wp,
    const float* __restrict__ bias, bf16* __restrict__ dst,
    int dpitch, int dbase, bool transposed, int tid) {
  constexpr int TC = NC / 4;
  constexpr int TR = 256 / TC;
  constexpr int NI = (Sd + TR - 1) / TR;
  const int tc = tid % TC, tr = tid / TC;
  const int c = tc * 4;
  float acc[NI][4];
#pragma unroll
  for (int i = 0; i < NI; ++i) acc[i][0] = acc[i][1] = acc[i][2] = acc[i][3] = 0.f;

  for (int k0 = 0; k0 < KD; k0 += 4) {
    unsigned short wv[4][4];
#pragma unroll
    for (int kk = 0; kk < 4; ++kk) {
      ushort4 t = *reinterpret_cast<const ushort4*>(&Wp[(k0 + kk) * NC + c]);
      wv[kk][0] = t.x; wv[kk][1] = t.y; wv[kk][2] = t.z; wv[kk][3] = t.w;
    }
#pragma unroll
    for (int i = 0; i < NI; ++i) {
      int r = tr + TR * i; if (r >= Sd) r = 0;
      ushort4 t = *reinterpret_cast<const ushort4*>(&A[r * KD + k0]);
      const unsigned short av[4] = {t.x, t.y, t.z, t.w};
#pragma unroll
      for (int kk = 0; kk < 4; ++kk) {
        const float a = bfr(av[kk]);
        acc[i][0] = fmaf(a, bfr(wv[kk][0]), acc[i][0]);
        acc[i][1] = fmaf(a, bfr(wv[kk][1]), acc[i][1]);
        acc[i][2] = fmaf(a, bfr(wv[kk][2]), acc[i][2]);
        acc[i][3] = fmaf(a, bfr(wv[kk][3]), acc[i][3]);
      }
    }
  }
  const float bx[4] = {bias[c], bias[c + 1], bias[c + 2], bias[c + 3]};
#pragma unroll
  for (int i = 0; i < NI; ++i) {
    const int r = tr + TR * i;
    if (r < Sd) {
      if (!transposed) {
#pragma unroll
        for (int j = 0; j < 4; ++j)
          dst[r * dpitch + dbase + c + j] = f2b(acc[i][j] + bx[j]);
      } else {
#pragma unroll
        for (int j = 0; j < 4; ++j)
          dst[(dbase + c + j) * dpitch + r] = f2b(acc[i][j] + bx[j]);
      }
    }
  }
}

// ---------------------------------------------------------------------------
// Mega-kernel: one block per (b,h). Projections -> scores -> gate fusion ->
// softmax -> PV, all in LDS. ctx written to global (d_out staging).
// ---------------------------------------------------------------------------
__global__ __launch_bounds__(256) void attn_mega(
    const float* __restrict__ input, const float* __restrict__ attrT,
    const float* __restrict__ posE, const float* __restrict__ mask,
    const float* __restrict__ Wq, const float* __restrict__ bq,
    const float* __restrict__ Wk, const float* __restrict__ bk,
    const float* __restrict__ Wv, const float* __restrict__ bv,
    const float* __restrict__ Wqp, const float* __restrict__ bqp,
    const float* __restrict__ Wkp, const float* __restrict__ bkp,
    const float* __restrict__ Wqa, const float* __restrict__ bqa,
    const float* __restrict__ Wka, const float* __restrict__ bka,
    const float* __restrict__ W1, const float* __restrict__ b1,
    const float* __restrict__ W2, float* __restrict__ ctx) {
  // Region A: QC [100][196] bf16 (Q|QP|AQ0|AQ1); later W1s [100][100] bf16 / Wv slice
  // Region B: KC [192][104] bf16 transposed (K|KP|AK0|AK1); later Vs[100][64] + inp2[100][128]
  // Region C: staging (inp/pos/attr [100][128] + W slice); later ST [100][400] bf16
  __shared__ __align__(16) char Abuf[39200];
  __shared__ __align__(16) char Bbuf[39936];
  __shared__ __align__(16) char Cbuf[80000];
  __shared__ float smallf[1000];  // e2s[0:400) gate[400:800) b1s[800:900) W2s[900:1000)

  bf16* const QC    = (bf16*)Abuf;
  bf16* const W1s   = (bf16*)Abuf;
  bf16* const WvS   = (bf16*)Abuf;
  bf16* const KC    = (bf16*)Bbuf;
  bf16* const Vs    = (bf16*)Bbuf;
  bf16* const inp2  = (bf16*)(Bbuf + 12800);
  bf16* const ST    = (bf16*)Cbuf;
  bf16* const inp_s = (bf16*)Cbuf;
  bf16* const Wsl   = (bf16*)(Cbuf + 25600);
  float* const e2s  = smallf;
  float* const gts  = smallf + 400;
  float* const b1s  = smallf + 800;
  float* const W2s  = smallf + 900;

  const int tid = threadIdx.x;
  const int bh = blockIdx.x;
  const int b = bh >> 1, h = bh & 1;
  const size_t row0 = (size_t)b * Sd;

  // ---------- item / positional projections ----------
  for (int idx = tid; idx < 12800; idx += 256)
    inp_s[idx] = f2b(input[row0 * 128 + idx]);
  for (int idx = tid; idx < 8192; idx += 256)
    Wsl[idx] = f2b(Wq[(idx >> 6) * 128 + h * 64 + (idx & 63)]);
  __syncthreads();
  proj_gemm<128, 64>(inp_s, Wsl, bq + h * 64, QC, 196, 0, false, tid);
  __syncthreads();
  for (int idx = tid; idx < 8192; idx += 256)
    Wsl[idx] = f2b(Wk[(idx >> 6) * 128 + h * 64 + (idx & 63)]);
  __syncthreads();
  proj_gemm<128, 64>(inp_s, Wsl, bk + h * 64, KC, 104, 0, true, tid);
  __syncthreads();

  for (int idx = tid; idx < 12800; idx += 256)
    inp_s[idx] = f2b(posE[row0 * 128 + idx]);
  for (int idx = tid; idx < 8192; idx += 256)
    Wsl[idx] = f2b(Wqp[(idx >> 6) * 128 + h * 64 + (idx & 63)]);
  __syncthreads();
  proj_gemm<128, 64>(inp_s, Wsl, bqp + h * 64, QC, 196, 64, false, tid);
  __syncthreads();
  for (int idx = tid; idx < 8192; idx += 256)
    Wsl[idx] = f2b(Wkp[(idx >> 6) * 128 + h * 64 + (idx & 63)]);
  __syncthreads();
  proj_gemm<128, 64>(inp_s, Wsl, bkp + h * 64, KC, 104, 64, true, tid);
  __syncthreads();

  // ---------- attribute projections ----------
  for (int f = 0; f < 2; ++f) {
    const size_t abase = (size_t)(f * B_ + b) * 6400;
    for (int idx = tid; idx < 6400; idx += 256)
      inp_s[idx] = f2b(attrT[abase + idx]);
    for (int idx = tid; idx < 2048; idx += 256)
      Wsl[idx] = f2b(Wqa[f * 4096 + (idx >> 5) * 64 + h * 32 + (idx & 31)]);
    __syncthreads();
    proj_gemm<64, 32>(inp_s, Wsl, bqa + f * 64 + h * 32, QC, 196, 128 + f * 32, false, tid);
    __syncthreads();
    for (int idx = tid; idx < 2048; idx += 256)
      Wsl[idx] = f2b(Wka[f * 4096 + (idx >> 5) * 64 + h * 32 + (idx & 31)]);
    __syncthreads();
    proj_gemm<64, 32>(inp_s, Wsl, bka + f * 64 + h * 32, KC, 104, 128 + f * 32, true, tid);
    __syncthreads();
  }

  // ---------- scores: ST[r][st*100 + k] ----------
  {
    const int wid = tid >> 6, l = tid & 63;
    const bool lv = (l < 50);
    const int kad = lv ? 2 * l : 0;
    for (int pass = 0; pass < 4; ++pass) {
      const int rb = pass * 32 + wid * 8;
#pragma unroll
      for (int st = 0; st < 4; ++st) {
        const int dbase = (st == 0) ? 128 : (st == 1) ? 160 : (st == 2) ? 0 : 64;
        const int dn = (st < 2) ? 32 : 64;
        float acc[8][2];
#pragma unroll
        for (int j = 0; j < 8; ++j) acc[j][0] = acc[j][1] = 0.f;
        for (int d0 = 0; d0 < dn; d0 += 4) {
          unsigned short kv[4][2];
#pragma unroll
          for (int kk = 0; kk < 4; ++kk) {
            ushort2 t = *reinterpret_cast<const ushort2*>(&KC[(dbase + d0 + kk) * 104 + kad]);
            kv[kk][0] = t.x; kv[kk][1] = t.y;
          }
#pragma unroll
          for (int j = 0; j < 8; ++j) {
            int r = rb + j; if (r >= Sd) r = 0;
            ushort4 t = *reinterpret_cast<const ushort4*>(&QC[r * 196 + dbase + d0]);
            const unsigned short qv[4] = {t.x, t.y, t.z, t.w};
#pragma unroll
            for (int kk = 0; kk < 4; ++kk) {
              const float a = bfr(qv[kk]);
              acc[j][0] = fmaf(a, bfr(kv[kk][0]), acc[j][0]);
              acc[j][1] = fmaf(a, bfr(kv[kk][1]), acc[j][1]);
            }
          }
        }
        if (lv) {
#pragma unroll
          for (int j = 0; j < 8; ++j) {
            const int r = rb + j;
            if (r < Sd) {
              ST[r * 400 + st * 100 + kad]     = f2b(acc[j][0]);
              ST[r * 400 + st * 100 + kad + 1] = f2b(acc[j][1]);
            }
          }
        }
      }
    }
  }
  __syncthreads();

  // ---------- gate fusion: e2 = relu(row @ W1 + b1) @ W2, softmax over st ----------
  for (int idx = tid; idx < 10000; idx += 256) W1s[idx] = f2b(W1[idx]);
  if (tid < 100) { b1s[tid] = b1[tid]; W2s[tid] = W2[tid]; }
  __syncthreads();
  {
    const int wid = tid >> 6, l = tid & 63;
    const bool lv = (l < 50);
    const int cad = lv ? 2 * l : 0;
    const float w2a = lv ? W2s[cad]     : 0.f;
    const float w2b = lv ? W2s[cad + 1] : 0.f;
    const float bba = lv ? b1s[cad]     : 0.f;
    const float bbb = lv ? b1s[cad + 1] : 0.f;
    for (int it = 0; it < 13; ++it) {
      const int gb = it * 32 + wid * 8;
      float acc[8][2];
#pragma unroll
      for (int j = 0; j < 8; ++j) acc[j][0] = acc[j][1] = 0.f;
      for (int k0 = 0; k0 < 100; k0 += 2) {
        const ushort2 t0 = *reinterpret_cast<const ushort2*>(&W1s[k0 * 100 + cad]);
        const ushort2 t1 = *reinterpret_cast<const ushort2*>(&W1s[(k0 + 1) * 100 + cad]);
        const float w00 = bfr(t0.x), w01 = bfr(t0.y);
        const float w10 = bfr(t1.x), w11 = bfr(t1.y);
#pragma unroll
        for (int j = 0; j < 8; ++j) {
          int g = gb + j; if (g >= 400) g = 0;
          const int roff = (g >> 2) * 400 + (g & 3) * 100;
          const ushort2 sv = *reinterpret_cast<const ushort2*>(&ST[roff + k0]);
          const float a0 = bfr(sv.x), a1 = bfr(sv.y);
          acc[j][0] = fmaf(a0, w00, fmaf(a1, w10, acc[j][0]));
          acc[j][1] = fmaf(a0, w01, fmaf(a1, w11, acc[j][1]));
        }
      }
#pragma unroll
      for (int j = 0; j < 8; ++j) {
        const int g = gb + j;
        float p = 0.f;
        if (lv) {
          const float e1a = fmaxf(acc[j][0] + bba, 0.f);
          const float e1b = fmaxf(acc[j][1] + bbb, 0.f);
          p = e1a * w2a + e1b * w2b;
        }
        p = wsum(p);
        if (l == 0 && g < 400) e2s[g] = p;
      }
    }
  }
  __syncthreads();
  if (tid < 100) {
    float e0 = e2s[tid * 4], e1 = e2s[tid * 4 + 1];
    float e2v = e2s[tid * 4 + 2], e3 = e2s[tid * 4 + 3];
    const float m = fmaxf(fmaxf(e0, e1), fmaxf(e2v, e3));
    e0 = __expf(e0 - m); e1 = __expf(e1 - m);
    e2v = __expf(e2v - m); e3 = __expf(e3 - m);
    const float inv = 1.0f / (e0 + e1 + e2v + e3);
    gts[tid * 4] = e0 * inv; gts[tid * 4 + 1] = e1 * inv;
    gts[tid * 4 + 2] = e2v * inv; gts[tid * 4 + 3] = e3 * inv;
  }
  __syncthreads();

  // ---------- fuse + scale + mask + softmax; P written in place into ST[r][0:100) ----------
  {
    const int wid = tid >> 6, l = tid & 63;
    for (int it = 0; it < 25; ++it) {
      const int r = it * 4 + wid;
      const float g0 = gts[r * 4], g1 = gts[r * 4 + 1];
      const float g2 = gts[r * 4 + 2], g3 = gts[r * 4 + 3];
      bf16* const sp = ST + r * 400;
      const float* const mp = mask + (size_t)b * 10000 + r * 100;
      float x1 = g0 * b2f(sp[l]) + g1 * b2f(sp[100 + l]) +
                 g2 * b2f(sp[200 + l]) + g3 * b2f(sp[300 + l]);
      x1 = x1 * 0.125f + mp[l];
      const bool v2 = (l < 36);
      float x2 = -3e38f;
      if (v2) {
        const int k2 = 64 + l;
        x2 = g0 * b2f(sp[k2]) + g1 * b2f(sp[100 + k2]) +
             g2 * b2f(sp[200 + k2]) + g3 * b2f(sp[300 + k2]);
        x2 = x2 * 0.125f + mp[k2];
      }
      const float M = wmax(fmaxf(x1, x2));
      const float ea = __expf(x1 - M);
      const float eb = v2 ? __expf(x2 - M) : 0.f;
      const float inv = 1.0f / wsum(ea + eb);
      sp[l] = f2b(ea * inv);
      if (v2) sp[64 + l] = f2b(eb * inv);
    }
  }
  __syncthreads();

  // ---------- V projection (re-stage input; QC/KC regions are dead) ----------
  for (int idx = tid; idx < 12800; idx += 256)
    inp2[idx] = f2b(input[row0 * 128 + idx]);
  for (int idx = tid; idx < 8192; idx += 256)
    WvS[idx] = f2b(Wv[(idx >> 6) * 128 + h * 64 + (idx & 63)]);
  __syncthreads();
  proj_gemm<128, 64>(inp2, WvS, bv + h * 64, Vs, 64, 0, false, tid);
  __syncthreads();

  // ---------- PV: ctx[r][h*64 + c] = sum_k P[r][k] * V[k][c] ----------
  {
    const int tr = tid >> 4, tc = tid & 15, cc = tc << 2;
    float acc[7][4];
#pragma unroll
    for (int i = 0; i < 7; ++i) acc[i][0] = acc[i][1] = acc[i][2] = acc[i][3] = 0.f;
    for (int k0 = 0; k0 < 100; k0 += 2) {
      const ushort4 tv0 = *reinterpret_cast<const ushort4*>(&Vs[k0 * 64 + cc]);
      const ushort4 tv1 = *reinterpret_cast<const ushort4*>(&Vs[(k0 + 1) * 64 + cc]);
      const float v00 = bfr(tv0.x), v01 = bfr(tv0.y), v02 = bfr(tv0.z), v03 = bfr(tv0.w);
      const float v10 = bfr(tv1.x), v11 = bfr(tv1.y), v12 = bfr(tv1.z), v13 = bfr(tv1.w);
#pragma unroll
      for (int i = 0; i < 7; ++i) {
        int r = tr + 16 * i; if (r >= Sd) r = 0;
        const ushort2 pv = *reinterpret_cast<const ushort2*>(&ST[r * 400 + k0]);
        const float p0 = bfr(pv.x), p1 = bfr(pv.y);
        acc[i][0] = fmaf(p0, v00, fmaf(p1, v10, acc[i][0]));
        acc[i][1] = fmaf(p0, v01, fmaf(p1, v11, acc[i][1]));
        acc[i][2] = fmaf(p0, v02, fmaf(p1, v12, acc[i][2]));
        acc[i][3] = fmaf(p0, v03, fmaf(p1, v13, acc[i][3]));
      }
    }
#pragma unroll
    for (int i = 0; i < 7; ++i) {
      const int r = tr + 16 * i;
      if (r < Sd) {
        float4 o;
        o.x = acc[i][0]; o.y = acc[i][1]; o.z = acc[i][2]; o.w = acc[i][3];
        *reinterpret_cast<float4*>(&ctx[(row0 + r) * 128 + h * 64 + cc]) = o;
      }
    }
  }
}

// ---------------------------------------------------------------------------
// Fused output dense + residual + LayerNorm (in place over d_out).
// Block = 64 rows x all 128 cols.
// ---------------------------------------------------------------------------
__global__ __launch_bounds__(256) void dense_ln(
    const float* __restrict__ ctxg, const float* __restrict__ Wd,
    const float* __restrict__ bd, const float* __restrict__ resid,
    const float* __restrict__ lng, const float* __restrict__ lnb,
    float* __restrict__ out) {
  __shared__ float As[64][68];
  __shared__ float Ws[64][132];
  const int tid = threadIdx.x;
  const size_t row0 = (size_t)blockIdx.x * 64;
  const int tr = tid >> 4, tc = tid & 15;
  float acc[4][8];
#pragma unroll
  for (int i = 0; i < 4; ++i)
#pragma unroll
    for (int j = 0; j < 8; ++j) acc[i][j] = 0.f;

  for (int k0 = 0; k0 < 128; k0 += 64) {
#pragma unroll
    for (int rep = 0; rep < 4; ++rep) {
      const int idx = tid + rep * 256;
      const int r = idx >> 4, c4 = (idx & 15) << 2;
      *reinterpret_cast<float4*>(&As[r][c4]) =
          *reinterpret_cast<const float4*>(&ctxg[(row0 + r) * 128 + k0 + c4]);
    }
#pragma unroll
    for (int rep = 0; rep < 8; ++rep) {
      const int idx = tid + rep * 256;
      const int r = idx >> 5, c4 = (idx & 31) << 2;
      *reinterpret_cast<float4*>(&Ws[r][c4]) =
          *reinterpret_cast<const float4*>(&Wd[(size_t)(k0 + r) * 128 + c4]);
    }
    __syncthreads();
#pragma unroll 4
    for (int kk = 0; kk < 64; ++kk) {
      const float4 w0 = *reinterpret_cast<const float4*>(&Ws[kk][tc << 2]);
      const float4 w1 = *reinterpret_cast<const float4*>(&Ws[kk][(tc << 2) + 64]);
#pragma unroll
      for (int i = 0; i < 4; ++i) {
        const float a = As[tr * 4 + i][kk];
        acc[i][0] = fmaf(a, w0.x, acc[i][0]);
        acc[i][1] = fmaf(a, w0.y, acc[i][1]);
        acc[i][2] = fmaf(a, w0.z, acc[i][2]);
        acc[i][3] = fmaf(a, w0.w, acc[i][3]);
        acc[i][4] = fmaf(a, w1.x, acc[i][4]);
        acc[i][5] = fmaf(a, w1.y, acc[i][5]);
        acc[i][6] = fmaf(a, w1.z, acc[i][6]);
        acc[i][7] = fmaf(a, w1.w, acc[i][7]);
      }
    }
    __syncthreads();
  }

  const int c0 = tc << 2;
#pragma unroll
  for (int i = 0; i < 4; ++i) {
    const size_t r = row0 + tr * 4 + i;
    const float4 r0 = *reinterpret_cast<const float4*>(&resid[r * 128 + c0]);
    const float4 r1 = *reinterpret_cast<const float4*>(&resid[r * 128 + c0 + 64]);
    float hv[8];
    hv[0] = acc[i][0] + bd[c0]      + r0.x;
    hv[1] = acc[i][1] + bd[c0 + 1]  + r0.y;
    hv[2] = acc[i][2] + bd[c0 + 2]  + r0.z;
    hv[3] = acc[i][3] + bd[c0 + 3]  + r0.w;
    hv[4] = acc[i][4] + bd[c0 + 64] + r1.x;
    hv[5] = acc[i][5] + bd[c0 + 65] + r1.y;
    hv[6] = acc[i][6] + bd[c0 + 66] + r1.z;
    hv[7] = acc[i][7] + bd[c0 + 67] + r1.w;
    float s = 0.f;
#pragma unroll
    for (int j = 0; j < 8; ++j) s += hv[j];
    s = sum16(s);
    const float mu = s * (1.0f / 128.0f);
    float vs = 0.f;
#pragma unroll
    for (int j = 0; j < 8; ++j) { const float d = hv[j] - mu; vs = fmaf(d, d, vs); }
    vs = sum16(vs);
    const float rstd = rsqrtf(vs * (1.0f / 128.0f) + 1e-12f);
#pragma unroll
    for (int j = 0; j < 8; ++j) {
      const int cj = (j < 4) ? (c0 + j) : (c0 + 60 + j);
      out[r * 128 + cj] = (hv[j] - mu) * rstd * lng[cj] + lnb[cj];
    }
  }
}

}  // namespace

extern "C" void kernel_launch(void* const* d_in, const int* in_sizes, int n_in,
                              void* d_out, int out_size, void* d_ws,
                              size_t ws_size, hipStream_t stream) {
  (void)in_sizes; (void)n_in; (void)out_size; (void)d_ws; (void)ws_size;

  const float* input = (const float*)d_in[0];
  const float* attrT = (const float*)d_in[1];
  const float* posE  = (const float*)d_in[2];
  const float* mask  = (const float*)d_in[3];
  const float* Wq  = (const float*)d_in[4];  const float* bq  = (const float*)d_in[5];
  const float* Wk  = (const float*)d_in[6];  const float* bk  = (const float*)d_in[7];
  const float* Wv  = (const float*)d_in[8];  const float* bv  = (const float*)d_in[9];
  const float* Wqp = (const float*)d_in[10]; const float* bqp = (const float*)d_in[11];
  const float* Wkp = (const float*)d_in[12]; const float* bkp = (const float*)d_in[13];
  const float* Wqa = (const float*)d_in[14]; const float* bqa = (const float*)d_in[15];
  const float* Wka = (const float*)d_in[16]; const float* bka = (const float*)d_in[17];
  const float* W1  = (const float*)d_in[18]; const float* b1  = (const float*)d_in[19];
  const float* W2  = (const float*)d_in[20];
  const float* Wd  = (const float*)d_in[22]; const float* bd  = (const float*)d_in[23];
  const float* lng = (const float*)d_in[24]; const float* lnb = (const float*)d_in[25];

  float* ctx = (float*)d_out;  // d_out doubles as ctx staging, then final output

  attn_mega<<<dim3(B_ * 2), dim3(256), 0, stream>>>(
      input, attrT, posE, mask, Wq, bq, Wk, bk, Wv, bv, Wqp, bqp, Wkp, bkp,
      Wqa, bqa, Wka, bka, W1, b1, W2, ctx);
  dense_ln<<<dim3(BS_ / 64), dim3(256), 0, stream>>>(
      ctx, Wd, bd, input, lng, lnb, ctx);
}

// Round 3
// 591.921 us; speedup vs baseline: 3.4061x; 3.4061x over previous
//
#include <hip/hip_runtime.h>
#include <hip/hip_bf16.h>

using bf16 = __hip_bfloat16;
using u16 = unsigned short;
typedef __attribute__((ext_vector_type(8))) short bf16x8;
typedef __attribute__((ext_vector_type(4))) float f32x4;

namespace {

constexpr int B_  = 1024;
constexpr int Sd  = 100;
constexpr int BS_ = B_ * Sd;

constexpr int STP = 420;   // ST q-row pitch (elems): 4*104+4 -> conflict-free frag reads
constexpr int STS = 104;   // per-stream pitch within a q-row
constexpr int QKP = 196;   // QC/KC pitch (192 data + 4 pad; 98 words % 32 = 2)
constexpr int AP  = 132;   // staging pitch for 128-wide operands
constexpr int ATP = 68;    // staging pitch for 64-wide attr operands

// LDS byte offsets (single 162,400 B arena, hand-aliased per phase)
constexpr int O_ST = 0;        // ST [100][420] bf16 = 84,000  (P1-P3: staging scratch)
constexpr int O_Q  = 84000;    // QC [100][196] bf16 = 39,200  (gate: e2s/gts f32[400]; P7: V staging)
constexpr int O_K  = 123200;   // KC [100][196] bf16 = 39,200  (gate: W1T [112][104]; P7: VT [64][104])
constexpr int LBYTES = 162400;

__device__ __forceinline__ float bfr(u16 u) {
  unsigned int x = ((unsigned int)u) << 16;
  float f; __builtin_memcpy(&f, &x, 4); return f;
}
__device__ __forceinline__ u16 f2bu(float x) {
  bf16 h = __float2bfloat16(x);
  u16 u; __builtin_memcpy(&u, &h, 2); return u;
}
__device__ __forceinline__ float wsum(float v) {
#pragma unroll
  for (int m = 32; m > 0; m >>= 1) v += __shfl_xor(v, m);
  return v;
}
__device__ __forceinline__ float wmax(float v) {
#pragma unroll
  for (int m = 32; m > 0; m >>= 1) v = fmaxf(v, __shfl_xor(v, m));
  return v;
}

__device__ __forceinline__ f32x4 MFMA(bf16x8 a, bf16x8 b, f32x4 c) {
  return __builtin_amdgcn_mfma_f32_16x16x32_bf16(a, b, c, 0, 0, 0);
}

// Fragment load: p = &M[idx][k0] per-lane row base + gq*4 already folded in by caller.
// elems 0..3 at +0, elems 4..7 at +16 (same mapping used for A and B -> k-perm cancels).
__device__ __forceinline__ bf16x8 ldf(const u16* p) {
  const ushort4 lo = *reinterpret_cast<const ushort4*>(p);
  const ushort4 hi = *reinterpret_cast<const ushort4*>(p + 16);
  bf16x8 f;
  f[0] = (short)lo.x; f[1] = (short)lo.y; f[2] = (short)lo.z; f[3] = (short)lo.w;
  f[4] = (short)hi.x; f[5] = (short)hi.y; f[6] = (short)hi.z; f[7] = (short)hi.w;
  return f;
}
// K-tail (k0=96, 4 valid k): only lane-group 0 elems 0..3 carry data (k-offsets 0..3
// under either candidate mapping); everything else zero.
__device__ __forceinline__ bf16x8 ldf_tail(const u16* p, bool valid) {
  bf16x8 f = {0, 0, 0, 0, 0, 0, 0, 0};
  if (valid) {
    const ushort4 lo = *reinterpret_cast<const ushort4*>(p);
    f[0] = (short)lo.x; f[1] = (short)lo.y; f[2] = (short)lo.z; f[3] = (short)lo.w;
  }
  return f;
}

// global f32 rows (contiguous, ncol wide) -> LDS bf16 [nrow][pitch]
__device__ __forceinline__ void stage_rows(const float* __restrict__ src, u16* dst,
                                           int ncol, int nrow, int pitch, int tid, int nthr) {
  for (int idx = tid; idx < nrow * ncol; idx += nthr) {
    const int rr = idx / ncol, cc = idx - rr * ncol;
    dst[rr * pitch + cc] = f2bu(src[rr * ncol + cc]);
  }
}
// W[k][coff+c] -> WT[c][k] bf16 (reads coalesced over c)
__device__ __forceinline__ void stage_wt(const float* __restrict__ W, int ldw, int coff,
                                         u16* dst, int ncols, int kd, int pitch, int tid, int nthr) {
  for (int idx = tid; idx < ncols * kd; idx += nthr) {
    const int k = idx / ncols, c = idx - k * ncols;
    dst[c * pitch + k] = f2bu(W[k * ldw + coff + c]);
  }
}

// MFMA projection: dst = A[100][KD] @ WT[N][KD]^T + bias. N = NT*16.
// TR=false: dst[row][dbase+col]; TR=true: dst[col][row] (for VT).
template <int KD, int NT, bool TR>
__device__ __forceinline__ void mproj(const u16* A, int apitch, const u16* Wt,
                                      const float* __restrict__ bias, u16* dst,
                                      int dpitch, int dbase, int tid) {
  const int l = tid & 63, w = tid >> 6;
  const int r = l & 15, gq = l >> 4;
  for (int t = w; t < 7 * NT; t += 8) {
    const int mt = t / NT, nt = t - mt * NT;
    const int m0 = mt * 16, n0 = nt * 16;
    const int ar = (m0 + r < Sd) ? (m0 + r) : (Sd - 1);
    const u16* ap = A + ar * apitch + gq * 4;
    const u16* bp = Wt + (n0 + r) * apitch + gq * 4;
    f32x4 acc = {0.f, 0.f, 0.f, 0.f};
#pragma unroll
    for (int k0 = 0; k0 < KD; k0 += 32)
      acc = MFMA(ldf(ap + k0), ldf(bp + k0), acc);
    const float bvv = bias[n0 + r];
#pragma unroll
    for (int i = 0; i < 4; ++i) {
      const int row = m0 + gq * 4 + i;
      if (row < Sd) {
        if (TR) dst[(n0 + r) * dpitch + dbase + row] = f2bu(acc[i] + bvv);
        else    dst[row * dpitch + dbase + n0 + r]   = f2bu(acc[i] + bvv);
      }
    }
  }
}

// ---------------------------------------------------------------------------
// Mega-kernel: one block per (b,h), 512 threads, all-MFMA GEMM phases.
// ---------------------------------------------------------------------------
__global__ __launch_bounds__(512) void attn_mega(
    const float* __restrict__ input, const float* __restrict__ attrT,
    const float* __restrict__ posE, const float* __restrict__ mask,
    const float* __restrict__ Wq, const float* __restrict__ bq,
    const float* __restrict__ Wk, const float* __restrict__ bk,
    const float* __restrict__ Wv, const float* __restrict__ bv,
    const float* __restrict__ Wqp, const float* __restrict__ bqp,
    const float* __restrict__ Wkp, const float* __restrict__ bkp,
    const float* __restrict__ Wqa, const float* __restrict__ bqa,
    const float* __restrict__ Wka, const float* __restrict__ bka,
    const float* __restrict__ W1, const float* __restrict__ b1,
    const float* __restrict__ W2, float* __restrict__ ctx) {
  __shared__ __align__(16) char L[LBYTES];
  u16* const ST = (u16*)(L + O_ST);             // [100][STP]: [q][st*104+k]
  u16* const QC = (u16*)(L + O_Q);              // [100][196]: q rows, d-cat
  u16* const KC = (u16*)(L + O_K);              // [100][196]: key rows, d-cat
  // phase-local aliases
  u16* const SA  = (u16*)(L + O_ST);            // staging A [100][132]
  u16* const SW1 = (u16*)(L + O_ST + 26400);    // staging WT [64][132]
  u16* const SW2 = (u16*)(L + O_ST + 43296);    // staging WT [64][132]
  u16* const AT0 = (u16*)(L + O_ST);            // attr0 [100][68]
  u16* const AT1 = (u16*)(L + O_ST + 13600);    // attr1 [100][68]
  u16* const WA0Q = (u16*)(L + O_ST + 27200);   // [32][68] x4
  u16* const WA0K = (u16*)(L + O_ST + 31552);
  u16* const WA1Q = (u16*)(L + O_ST + 35904);
  u16* const WA1K = (u16*)(L + O_ST + 40256);
  float* const e2s = (float*)(L + O_Q);         // [400] (gate logits -> gate weights)
  u16* const W1T = (u16*)(L + O_K);             // [112][104], zero-padded
  u16* const VA  = (u16*)(L + O_Q);             // V-proj input staging [100][132]
  u16* const WVT = (u16*)(L + O_Q + 26400);     // [64][132] (spills 4,096 into dead O_K)
  u16* const VT  = (u16*)(L + O_K + 8192);      // [64][104]: VT[c][s]

  const int tid = threadIdx.x;
  const int bh = blockIdx.x;
  const int b = bh >> 1, h = bh & 1;
  const size_t row0 = (size_t)b * Sd;
  const int l = tid & 63, w = tid >> 6;
  const int r = l & 15, gq = l >> 4;

  // ---------- P1: Q/K projections ----------
  stage_rows(input + row0 * 128, SA, 128, 100, AP, tid, 512);
  stage_wt(Wq, 128, h * 64, SW1, 64, 128, AP, tid, 512);
  stage_wt(Wk, 128, h * 64, SW2, 64, 128, AP, tid, 512);
  __syncthreads();
  mproj<128, 4, false>(SA, AP, SW1, bq + h * 64, QC, QKP, 0, tid);
  mproj<128, 4, false>(SA, AP, SW2, bk + h * 64, KC, QKP, 0, tid);
  __syncthreads();

  // ---------- P2: QP/KP projections ----------
  stage_rows(posE + row0 * 128, SA, 128, 100, AP, tid, 512);
  stage_wt(Wqp, 128, h * 64, SW1, 64, 128, AP, tid, 512);
  stage_wt(Wkp, 128, h * 64, SW2, 64, 128, AP, tid, 512);
  __syncthreads();
  mproj<128, 4, false>(SA, AP, SW1, bqp + h * 64, QC, QKP, 64, tid);
  mproj<128, 4, false>(SA, AP, SW2, bkp + h * 64, KC, QKP, 64, tid);
  __syncthreads();

  // ---------- P3: attribute projections ----------
  stage_rows(attrT + (size_t)b * 6400, AT0, 64, 100, ATP, tid, 512);
  stage_rows(attrT + (size_t)(B_ + b) * 6400, AT1, 64, 100, ATP, tid, 512);
  stage_wt(Wqa, 64, h * 32, WA0Q, 32, 64, ATP, tid, 512);
  stage_wt(Wka, 64, h * 32, WA0K, 32, 64, ATP, tid, 512);
  stage_wt(Wqa + 4096, 64, h * 32, WA1Q, 32, 64, ATP, tid, 512);
  stage_wt(Wka + 4096, 64, h * 32, WA1K, 32, 64, ATP, tid, 512);
  __syncthreads();
  mproj<64, 2, false>(AT0, ATP, WA0Q, bqa + h * 32, QC, QKP, 128, tid);
  mproj<64, 2, false>(AT0, ATP, WA0K, bka + h * 32, KC, QKP, 128, tid);
  mproj<64, 2, false>(AT1, ATP, WA1Q, bqa + 64 + h * 32, QC, QKP, 160, tid);
  mproj<64, 2, false>(AT1, ATP, WA1K, bka + 64 + h * 32, KC, QKP, 160, tid);
  __syncthreads();

  // ---------- P4: 4-stream scores -> ST (st: 0=attr0 d128, 1=attr1 d160, 2=item d0, 3=pos d64) ----------
  for (int t = w; t < 49; t += 8) {
    const int mt = t / 7, nt = t - mt * 7;
    const int m0 = mt * 16, n0 = nt * 16;
    const int ar = (m0 + r < Sd) ? (m0 + r) : (Sd - 1);
    const int br = (n0 + r < Sd) ? (n0 + r) : (Sd - 1);
    const u16* ap = QC + ar * QKP + gq * 4;
    const u16* bp = KC + br * QKP + gq * 4;
    f32x4 a0 = {0.f, 0.f, 0.f, 0.f}, a1 = a0, a2 = a0, a3 = a0;
    a2 = MFMA(ldf(ap + 0),   ldf(bp + 0),   a2);
    a2 = MFMA(ldf(ap + 32),  ldf(bp + 32),  a2);
    a3 = MFMA(ldf(ap + 64),  ldf(bp + 64),  a3);
    a3 = MFMA(ldf(ap + 96),  ldf(bp + 96),  a3);
    a0 = MFMA(ldf(ap + 128), ldf(bp + 128), a0);
    a1 = MFMA(ldf(ap + 160), ldf(bp + 160), a1);
    const int col = n0 + r;
    if (col < Sd) {
#pragma unroll
      for (int i = 0; i < 4; ++i) {
        const int row = m0 + gq * 4 + i;
        if (row < Sd) {
          u16* sp = ST + row * STP + col;
          sp[0]       = f2bu(a0[i]);
          sp[STS]     = f2bu(a1[i]);
          sp[2 * STS] = f2bu(a2[i]);
          sp[3 * STS] = f2bu(a3[i]);
        }
      }
    }
  }
  __syncthreads();

  // ---------- P5: gate fusion e2 = relu(ST@W1 + b1)@W2, softmax over st ----------
  for (int idx = tid; idx < 112 * 104; idx += 512) {
    const int c = idx / 104, k = idx - c * 104;
    W1T[c * 104 + k] = (c < Sd && k < Sd) ? f2bu(W1[k * Sd + c]) : (u16)0;
  }
  __syncthreads();
  for (int mt = w; mt < 25; mt += 8) {
    const int g0 = mt * 16;
    const int ga = g0 + r;  // stacked row = q*4 + st
    const u16* ap = ST + (ga >> 2) * STP + (ga & 3) * STS + gq * 4;
    float e0 = 0.f, e1 = 0.f, e2p = 0.f, e3 = 0.f;
    for (int nt = 0; nt < 7; ++nt) {
      const int n0 = nt * 16;
      const u16* bp = W1T + (n0 + r) * 104 + gq * 4;
      f32x4 acc = {0.f, 0.f, 0.f, 0.f};
      acc = MFMA(ldf(ap + 0),  ldf(bp + 0),  acc);
      acc = MFMA(ldf(ap + 32), ldf(bp + 32), acc);
      acc = MFMA(ldf(ap + 64), ldf(bp + 64), acc);
      acc = MFMA(ldf_tail(ap + 96, gq == 0), ldf_tail(bp + 96, gq == 0), acc);
      const int c = n0 + r;
      const float w2v = (c < Sd) ? W2[c] : 0.f;
      const float b1v = (c < Sd) ? b1[c] : 0.f;
      e0  += fmaxf(acc[0] + b1v, 0.f) * w2v;
      e1  += fmaxf(acc[1] + b1v, 0.f) * w2v;
      e2p += fmaxf(acc[2] + b1v, 0.f) * w2v;
      e3  += fmaxf(acc[3] + b1v, 0.f) * w2v;
    }
#pragma unroll
    for (int m = 1; m < 16; m <<= 1) {
      e0  += __shfl_xor(e0, m);
      e1  += __shfl_xor(e1, m);
      e2p += __shfl_xor(e2p, m);
      e3  += __shfl_xor(e3, m);
    }
    if (r == 0) {
      e2s[g0 + gq * 4 + 0] = e0;
      e2s[g0 + gq * 4 + 1] = e1;
      e2s[g0 + gq * 4 + 2] = e2p;
      e2s[g0 + gq * 4 + 3] = e3;
    }
  }
  __syncthreads();
  if (tid < Sd) {
    float v0 = e2s[tid * 4], v1 = e2s[tid * 4 + 1];
    float v2 = e2s[tid * 4 + 2], v3 = e2s[tid * 4 + 3];
    const float m = fmaxf(fmaxf(v0, v1), fmaxf(v2, v3));
    v0 = __expf(v0 - m); v1 = __expf(v1 - m);
    v2 = __expf(v2 - m); v3 = __expf(v3 - m);
    const float inv = 1.0f / (v0 + v1 + v2 + v3);
    e2s[tid * 4] = v0 * inv; e2s[tid * 4 + 1] = v1 * inv;
    e2s[tid * 4 + 2] = v2 * inv; e2s[tid * 4 + 3] = v3 * inv;
  }
  __syncthreads();

  // ---------- P6: fuse + scale + mask + row softmax; P in place at ST[q][0..99] ----------
  for (int q = w; q < Sd; q += 8) {
    const float g0v = e2s[q * 4], g1v = e2s[q * 4 + 1];
    const float g2v = e2s[q * 4 + 2], g3v = e2s[q * 4 + 3];
    u16* const sp = ST + q * STP;
    const float* const mp = mask + (size_t)b * 10000 + q * 100;
    float x1 = g0v * bfr(sp[l]) + g1v * bfr(sp[STS + l]) +
               g2v * bfr(sp[2 * STS + l]) + g3v * bfr(sp[3 * STS + l]);
    x1 = x1 * 0.125f + mp[l];
    const bool v2 = (l < 36);
    float x2 = -3e38f;
    if (v2) {
      const int k2 = 64 + l;
      x2 = g0v * bfr(sp[k2]) + g1v * bfr(sp[STS + k2]) +
           g2v * bfr(sp[2 * STS + k2]) + g3v * bfr(sp[3 * STS + k2]);
      x2 = x2 * 0.125f + mp[k2];
    }
    const float M = wmax(fmaxf(x1, x2));
    const float ea = __expf(x1 - M);
    const float eb = v2 ? __expf(x2 - M) : 0.f;
    const float inv = 1.0f / wsum(ea + eb);
    sp[l] = f2bu(ea * inv);
    if (v2) sp[64 + l] = f2bu(eb * inv);
  }
  __syncthreads();

  // ---------- P7: V projection -> VT[c][s] ----------
  stage_rows(input + row0 * 128, VA, 128, 100, AP, tid, 512);
  stage_wt(Wv, 128, h * 64, WVT, 64, 128, AP, tid, 512);
  __syncthreads();
  mproj<128, 4, true>(VA, AP, WVT, bv + h * 64, VT, STS, 0, tid);
  __syncthreads();

  // ---------- P8: PV -> ctx (global f32) ----------
  for (int t = w; t < 28; t += 8) {
    const int mt = t >> 2, nt = t & 3;
    const int m0 = mt * 16, n0 = nt * 16;
    const int ar = (m0 + r < Sd) ? (m0 + r) : (Sd - 1);
    const u16* ap = ST + ar * STP + gq * 4;
    const u16* bp = VT + (n0 + r) * STS + gq * 4;
    f32x4 acc = {0.f, 0.f, 0.f, 0.f};
    acc = MFMA(ldf(ap + 0),  ldf(bp + 0),  acc);
    acc = MFMA(ldf(ap + 32), ldf(bp + 32), acc);
    acc = MFMA(ldf(ap + 64), ldf(bp + 64), acc);
    acc = MFMA(ldf_tail(ap + 96, gq == 0), ldf_tail(bp + 96, gq == 0), acc);
#pragma unroll
    for (int i = 0; i < 4; ++i) {
      const int row = m0 + gq * 4 + i;
      if (row < Sd)
        ctx[(row0 + row) * 128 + h * 64 + n0 + r] = acc[i];
    }
  }
}

// ---------------------------------------------------------------------------
// Output dense (MFMA) + bias + residual + LayerNorm, in place over d_out.
// 256 threads, 64 rows/block.
// ---------------------------------------------------------------------------
__global__ __launch_bounds__(256) void dense_ln(
    const float* __restrict__ ctxg, const float* __restrict__ Wd,
    const float* __restrict__ bd, const float* __restrict__ resid,
    const float* __restrict__ lng, const float* __restrict__ lnb,
    float* __restrict__ out) {
  __shared__ __align__(16) char L[84480];
  u16* const Ab  = (u16*)L;             // [64][132] bf16
  u16* const WdT = (u16*)(L + 16896);   // [128][132] bf16
  float* const Hs = (float*)(L + 50688);// [64][132] f32
  const int tid = threadIdx.x;
  const size_t row0 = (size_t)blockIdx.x * 64;

  for (int idx = tid; idx < 64 * 128; idx += 256) {
    const int rr = idx >> 7, cc = idx & 127;
    Ab[rr * AP + cc] = f2bu(ctxg[(row0 + rr) * 128 + cc]);
  }
  for (int idx = tid; idx < 128 * 128; idx += 256) {
    const int k = idx >> 7, c = idx & 127;
    WdT[c * AP + k] = f2bu(Wd[k * 128 + c]);
  }
  __syncthreads();

  const int l = tid & 63, w = tid >> 6, r = l & 15, gq = l >> 4;
  for (int t = w; t < 32; t += 4) {
    const int mt = t >> 3, nt = t & 7;
    const int m0 = mt * 16, n0 = nt * 16;
    const u16* ap = Ab + (m0 + r) * AP + gq * 4;
    const u16* bp = WdT + (n0 + r) * AP + gq * 4;
    f32x4 acc = {0.f, 0.f, 0.f, 0.f};
#pragma unroll
    for (int k0 = 0; k0 < 128; k0 += 32)
      acc = MFMA(ldf(ap + k0), ldf(bp + k0), acc);
#pragma unroll
    for (int i = 0; i < 4; ++i)
      Hs[(m0 + gq * 4 + i) * AP + n0 + r] = acc[i];
  }
  __syncthreads();

  for (int rr = w; rr < 64; rr += 4) {
    const size_t grow = row0 + rr;
    const float h1 = Hs[rr * AP + l]      + bd[l]      + resid[grow * 128 + l];
    const float h2 = Hs[rr * AP + 64 + l] + bd[64 + l] + resid[grow * 128 + 64 + l];
    const float mu = wsum(h1 + h2) * (1.0f / 128.0f);
    const float d1 = h1 - mu, d2 = h2 - mu;
    const float var = wsum(d1 * d1 + d2 * d2) * (1.0f / 128.0f);
    const float rs = rsqrtf(var + 1e-12f);
    out[grow * 128 + l]      = d1 * rs * lng[l]      + lnb[l];
    out[grow * 128 + 64 + l] = d2 * rs * lng[64 + l] + lnb[64 + l];
  }
}

}  // namespace

extern "C" void kernel_launch(void* const* d_in, const int* in_sizes, int n_in,
                              void* d_out, int out_size, void* d_ws,
                              size_t ws_size, hipStream_t stream) {
  (void)in_sizes; (void)n_in; (void)out_size; (void)d_ws; (void)ws_size;

  const float* input = (const float*)d_in[0];
  const float* attrT = (const float*)d_in[1];
  const float* posE  = (const float*)d_in[2];
  const float* mask  = (const float*)d_in[3];
  const float* Wq  = (const float*)d_in[4];  const float* bq  = (const float*)d_in[5];
  const float* Wk  = (const float*)d_in[6];  const float* bk  = (const float*)d_in[7];
  const float* Wv  = (const float*)d_in[8];  const float* bv  = (const float*)d_in[9];
  const float* Wqp = (const float*)d_in[10]; const float* bqp = (const float*)d_in[11];
  const float* Wkp = (const float*)d_in[12]; const float* bkp = (const float*)d_in[13];
  const float* Wqa = (const float*)d_in[14]; const float* bqa = (const float*)d_in[15];
  const float* Wka = (const float*)d_in[16]; const float* bka = (const float*)d_in[17];
  const float* W1  = (const float*)d_in[18]; const float* b1  = (const float*)d_in[19];
  const float* W2  = (const float*)d_in[20];
  const float* Wd  = (const float*)d_in[22]; const float* bd  = (const float*)d_in[23];
  const float* lng = (const float*)d_in[24]; const float* lnb = (const float*)d_in[25];

  float* ctx = (float*)d_out;  // d_out doubles as ctx staging, then final output

  attn_mega<<<dim3(B_ * 2), dim3(512), 0, stream>>>(
      input, attrT, posE, mask, Wq, bq, Wk, bk, Wv, bv, Wqp, bqp, Wkp, bkp,
      Wqa, bqa, Wka, bka, W1, b1, W2, ctx);
  dense_ln<<<dim3(BS_ / 64), dim3(256), 0, stream>>>(
      ctx, Wd, bd, input, lng, lnb, ctx);
}

// Round 4
// 562.543 us; speedup vs baseline: 3.5839x; 1.0522x over previous
//
#include <hip/hip_runtime.h>
#include <hip/hip_bf16.h>

using bf16 = __hip_bfloat16;
using u16 = unsigned short;
typedef __attribute__((ext_vector_type(8))) short bf16x8;
typedef __attribute__((ext_vector_type(16))) float f32x16;

namespace {

constexpr int B_  = 1024;
constexpr int Sd  = 100;
constexpr int BS_ = B_ * Sd;

constexpr int STP = 420;   // ST q-row pitch (elems); 210 words % 32 = 18 -> 2-way (free)
constexpr int STS = 104;   // per-stream pitch inside a q-row
constexpr int QKP = 196;   // QC/KC pitch; 98 words % 32 = 2 -> 2-way
constexpr int AP  = 132;   // 128-wide staging pitch; 66 words % 32 = 2
constexpr int ATP = 68;    // 64-wide attr staging pitch; 34 words % 32 = 2
constexpr int W1P = 116;   // W1T pitch; 58 words % 32 = 26 -> 2-way (112 would be 8-way)
constexpr int VTP = 116;

constexpr int O_ST = 0;        // ST [100][420] bf16 = 84,000 B (P1-P3: staging scratch)
constexpr int O_Q  = 84000;    // QC [100][196] = 39,200 (gate: guard+e2s; P7: VA)
constexpr int O_K  = 123200;   // KC [100][196] = 39,200 (gate: W1T; P7/P8: WVT spill + VT)
constexpr int LBYTES = 162400;

__device__ __forceinline__ float bfr(u16 u) {
  unsigned int x = ((unsigned int)u) << 16;
  float f; __builtin_memcpy(&f, &x, 4); return f;
}
__device__ __forceinline__ u16 f2bu(float x) {
  bf16 h = __float2bfloat16(x);
  u16 u; __builtin_memcpy(&u, &h, 2); return u;
}
__device__ __forceinline__ float wsum(float v) {
#pragma unroll
  for (int m = 32; m > 0; m >>= 1) v += __shfl_xor(v, m);
  return v;
}
__device__ __forceinline__ float wmax(float v) {
#pragma unroll
  for (int m = 32; m > 0; m >>= 1) v = fmaxf(v, __shfl_xor(v, m));
  return v;
}

__device__ __forceinline__ f32x16 zf16() {
  f32x16 z;
#pragma unroll
  for (int i = 0; i < 16; ++i) z[i] = 0.f;
  return z;
}
__device__ __forceinline__ f32x16 MFMA32(bf16x8 a, bf16x8 b, f32x16 c) {
  return __builtin_amdgcn_mfma_f32_32x32x16_bf16(a, b, c, 0, 0, 0);
}

// 8 contiguous bf16 at p (8B-aligned) as two b64 reads. Same helper for A and B
// operands -> any k-permutation inside the 16-wide block cancels in the MFMA.
__device__ __forceinline__ bf16x8 ld8(const u16* p) {
  const ushort4 a = *reinterpret_cast<const ushort4*>(p);
  const ushort4 b = *reinterpret_cast<const ushort4*>(p + 4);
  bf16x8 f;
  f[0] = (short)a.x; f[1] = (short)a.y; f[2] = (short)a.z; f[3] = (short)a.w;
  f[4] = (short)b.x; f[5] = (short)b.y; f[6] = (short)b.z; f[7] = (short)b.w;
  return f;
}

// global f32 rows (contiguous, ncol = 4<<L4) -> LDS bf16 [nrow][pitch], float4-vectorized
template <int L4>
__device__ __forceinline__ void stage_rows4(const float* __restrict__ src, u16* dst,
                                            int nrow, int pitch, int tid, int nthr) {
  for (int i = tid; i < (nrow << L4); i += nthr) {
    const int rr = i >> L4, cc = (i & ((1 << L4) - 1)) << 2;
    const float4 v = *reinterpret_cast<const float4*>(src + ((size_t)rr << (L4 + 2)) + cc);
    ushort4 o;
    o.x = f2bu(v.x); o.y = f2bu(v.y); o.z = f2bu(v.z); o.w = f2bu(v.w);
    *reinterpret_cast<ushort4*>(dst + rr * pitch + cc) = o;
  }
}
// W[k][coff+c] -> WT[c][k] bf16 (reads coalesced over c); NC = 1<<LC columns
template <int LC>
__device__ __forceinline__ void stage_wt(const float* __restrict__ W, int ldw, int coff,
                                         u16* dst, int kd, int pitch, int tid, int nthr) {
  constexpr int NC = 1 << LC;
  for (int idx = tid; idx < NC * kd; idx += nthr) {
    const int k = idx >> LC, c = idx & (NC - 1);
    dst[c * pitch + k] = f2bu(W[k * ldw + coff + c]);
  }
}

// One 32x32 output tile: dst = A[100][KD] @ Wt[N][KD]^T + bias.
// TR=false: dst[row][dbase+n0+col]; TR=true: dst[n0+col][dbase+row].
template <int KD, bool TR>
__device__ __forceinline__ void tile32(const u16* A, int apitch, const u16* Wt, int wpitch,
                                       const float* __restrict__ bias, u16* dst, int dpitch,
                                       int dbase, int m0, int n0, int l) {
  const int cr = l & 31, g = l >> 5;
  int ar = m0 + cr; if (ar >= Sd) ar = Sd - 1;
  const u16* ap = A + ar * apitch + g * 8;
  const u16* bp = Wt + (n0 + cr) * wpitch + g * 8;
  f32x16 acc = zf16();
#pragma unroll
  for (int k0 = 0; k0 < KD; k0 += 16)
    acc = MFMA32(ld8(ap + k0), ld8(bp + k0), acc);
  const float bvv = bias[n0 + cr];
#pragma unroll
  for (int i = 0; i < 16; ++i) {
    const int row = m0 + (i & 3) + 8 * (i >> 2) + 4 * g;  // C/D: col=lane&31 (measured)
    if (row < Sd) {
      if (TR) dst[(n0 + cr) * dpitch + dbase + row] = f2bu(acc[i] + bvv);
      else    dst[row * dpitch + dbase + n0 + cr]   = f2bu(acc[i] + bvv);
    }
  }
}

// ---------------------------------------------------------------------------
// Mega-kernel: one block per (b,h), 512 threads, 32x32x16 MFMA everywhere.
// ---------------------------------------------------------------------------
__global__ __launch_bounds__(512) void attn_mega(
    const float* __restrict__ input, const float* __restrict__ attrT,
    const float* __restrict__ posE, const float* __restrict__ mask,
    const float* __restrict__ Wq, const float* __restrict__ bq,
    const float* __restrict__ Wk, const float* __restrict__ bk,
    const float* __restrict__ Wv, const float* __restrict__ bv,
    const float* __restrict__ Wqp, const float* __restrict__ bqp,
    const float* __restrict__ Wkp, const float* __restrict__ bkp,
    const float* __restrict__ Wqa, const float* __restrict__ bqa,
    const float* __restrict__ Wka, const float* __restrict__ bka,
    const float* __restrict__ W1, const float* __restrict__ b1,
    const float* __restrict__ W2, float* __restrict__ ctx) {
  __shared__ __align__(16) char L[LBYTES];
  u16* const ST = (u16*)(L + O_ST);            // [100][420]: [q][st*104+k]
  u16* const QC = (u16*)(L + O_Q);             // [100][196]
  u16* const KC = (u16*)(L + O_K);             // [100][196]
  // P1/P2 staging (in ST area)
  u16* const SA  = (u16*)(L + O_ST);           // [100][132]
  u16* const SW1 = (u16*)(L + O_ST + 26400);   // [64][132]
  u16* const SW2 = (u16*)(L + O_ST + 43296);   // [64][132]
  // P3 staging (in ST area)
  u16* const AT0  = (u16*)(L + O_ST);          // [100][68]
  u16* const AT1  = (u16*)(L + O_ST + 13600);
  u16* const WA0Q = (u16*)(L + O_ST + 27200);  // [32][68] x4
  u16* const WA0K = (u16*)(L + O_ST + 31552);
  u16* const WA1Q = (u16*)(L + O_ST + 35904);
  u16* const WA1K = (u16*)(L + O_ST + 40256);
  // gate phase
  float* const e2s = (float*)(L + O_Q + 16);   // [400]; first 16 B of O_Q = zero guard
  u16* const W1T = (u16*)(L + O_K);            // [128][116], zero outside (c<100 && k<100)
  // V phase
  u16* const VA  = (u16*)(L + O_Q);            // [100][132]
  u16* const WVT = (u16*)(L + O_Q + 26400);    // [64][132] (spills 4,096 B into dead W1T)
  u16* const VT  = (u16*)(L + O_K + 8192);     // [64][116], k-cols >=100 zeroed

  const int tid = threadIdx.x;
  const int bh = blockIdx.x;
  const int b = bh >> 1, h = bh & 1;
  const size_t row0 = (size_t)b * Sd;
  const int l = tid & 63, w = tid >> 6;
  const int cr = l & 31, g = l >> 5;

  // ---------- P1: Q/K projections ----------
  stage_rows4<5>(input + row0 * 128, SA, 100, AP, tid, 512);
  stage_wt<6>(Wq, 128, h * 64, SW1, 128, AP, tid, 512);
  stage_wt<6>(Wk, 128, h * 64, SW2, 128, AP, tid, 512);
  __syncthreads();
  for (int u = w; u < 16; u += 8) {
    const int pr = u >> 3, mt = (u >> 1) & 3, nt = u & 1;
    tile32<128, false>(SA, AP, pr ? SW2 : SW1, AP, (pr ? bk : bq) + h * 64,
                       pr ? KC : QC, QKP, 0, mt * 32, nt * 32, l);
  }
  __syncthreads();

  // ---------- P2: QP/KP projections ----------
  stage_rows4<5>(posE + row0 * 128, SA, 100, AP, tid, 512);
  stage_wt<6>(Wqp, 128, h * 64, SW1, 128, AP, tid, 512);
  stage_wt<6>(Wkp, 128, h * 64, SW2, 128, AP, tid, 512);
  __syncthreads();
  for (int u = w; u < 16; u += 8) {
    const int pr = u >> 3, mt = (u >> 1) & 3, nt = u & 1;
    tile32<128, false>(SA, AP, pr ? SW2 : SW1, AP, (pr ? bkp : bqp) + h * 64,
                       pr ? KC : QC, QKP, 64, mt * 32, nt * 32, l);
  }
  __syncthreads();

  // ---------- P3: attribute projections ----------
  stage_rows4<4>(attrT + (size_t)b * 6400, AT0, 100, ATP, tid, 512);
  stage_rows4<4>(attrT + (size_t)(B_ + b) * 6400, AT1, 100, ATP, tid, 512);
  stage_wt<5>(Wqa, 64, h * 32, WA0Q, 64, ATP, tid, 512);
  stage_wt<5>(Wka, 64, h * 32, WA0K, 64, ATP, tid, 512);
  stage_wt<5>(Wqa + 4096, 64, h * 32, WA1Q, 64, ATP, tid, 512);
  stage_wt<5>(Wka + 4096, 64, h * 32, WA1K, 64, ATP, tid, 512);
  __syncthreads();
  for (int u = w; u < 16; u += 8) {
    const int pr = u >> 2, mt = u & 3;  // 0=A0Q 1=A0K 2=A1Q 3=A1K
    const u16* Asrc = (pr < 2) ? AT0 : AT1;
    const u16* Wt = (pr == 0) ? WA0Q : (pr == 1) ? WA0K : (pr == 2) ? WA1Q : WA1K;
    const float* bs = (pr == 0) ? bqa + h * 32 : (pr == 1) ? bka + h * 32
                     : (pr == 2) ? bqa + 64 + h * 32 : bka + 64 + h * 32;
    tile32<64, false>(Asrc, ATP, Wt, ATP, bs, (pr & 1) ? KC : QC, QKP,
                      128 + (pr >> 1) * 32, mt * 32, 0, l);
  }
  __syncthreads();

  // ---------- P4: 4-stream scores -> ST; also finite-fill row pads 416..419 ----------
  {
    ushort4 z; z.x = z.y = z.z = z.w = 0;
    for (int q = tid; q < Sd; q += 512)
      *reinterpret_cast<ushort4*>(ST + q * STP + 416) = z;
  }
  for (int u = w; u < 16; u += 8) {
    const int mt = u >> 2, nt = u & 3;
    const int m0 = mt * 32, n0 = nt * 32;
    int ar = m0 + cr; if (ar >= Sd) ar = Sd - 1;
    int br = n0 + cr; if (br >= Sd) br = Sd - 1;
    const u16* ap = QC + ar * QKP + g * 8;
    const u16* bp = KC + br * QKP + g * 8;
    f32x16 ai = zf16(), po = zf16(), a0 = zf16(), a1 = zf16();
    ai = MFMA32(ld8(ap + 0),   ld8(bp + 0),   ai);
    ai = MFMA32(ld8(ap + 16),  ld8(bp + 16),  ai);
    ai = MFMA32(ld8(ap + 32),  ld8(bp + 32),  ai);
    ai = MFMA32(ld8(ap + 48),  ld8(bp + 48),  ai);
    po = MFMA32(ld8(ap + 64),  ld8(bp + 64),  po);
    po = MFMA32(ld8(ap + 80),  ld8(bp + 80),  po);
    po = MFMA32(ld8(ap + 96),  ld8(bp + 96),  po);
    po = MFMA32(ld8(ap + 112), ld8(bp + 112), po);
    a0 = MFMA32(ld8(ap + 128), ld8(bp + 128), a0);
    a0 = MFMA32(ld8(ap + 144), ld8(bp + 144), a0);
    a1 = MFMA32(ld8(ap + 160), ld8(bp + 160), a1);
    a1 = MFMA32(ld8(ap + 176), ld8(bp + 176), a1);
    const int col = n0 + cr;
    if (col < STS) {  // write pads 100..103 too (finite fill for gate's k-spill)
#pragma unroll
      for (int i = 0; i < 16; ++i) {
        const int row = m0 + (i & 3) + 8 * (i >> 2) + 4 * g;
        if (row < Sd) {
          u16* sp = ST + row * STP + col;
          sp[0]       = f2bu(a0[i]);   // attr0
          sp[STS]     = f2bu(a1[i]);   // attr1
          sp[2 * STS] = f2bu(ai[i]);   // item
          sp[3 * STS] = f2bu(po[i]);   // pos
        }
      }
    }
  }
  __syncthreads();

  // ---------- P5: gate fusion e2 = relu(ST@W1 + b1)@W2, softmax over st ----------
  for (int idx = tid; idx < 128 * 128; idx += 512) {
    const int c = idx & 127, k = idx >> 7;
    if (k < W1P)
      W1T[c * W1P + k] = (c < Sd && k < Sd) ? f2bu(W1[k * Sd + c]) : (u16)0;
  }
  if (tid < 8) ((u16*)(L + O_Q))[tid] = 0;  // guard: q=99/st=3 k-spill reads past ST
  __syncthreads();
  {
    float b1v[4], w2v[4];
#pragma unroll
    for (int nt = 0; nt < 4; ++nt) {
      const int c = nt * 32 + cr;
      b1v[nt] = (c < Sd) ? b1[c] : 0.f;
      w2v[nt] = (c < Sd) ? W2[c] : 0.f;
    }
    for (int mt = w; mt < 13; mt += 8) {
      const int m0 = mt * 32;
      int gr = m0 + cr; if (gr > 399) gr = 399;
      const u16* ap = ST + (gr >> 2) * STP + (gr & 3) * STS + g * 8;
      f32x16 c0 = zf16(), c1 = zf16(), c2 = zf16(), c3 = zf16();
#pragma unroll
      for (int k0 = 0; k0 < 112; k0 += 16) {
        const bf16x8 af = ld8(ap + k0);
        c0 = MFMA32(af, ld8(W1T + (cr)      * W1P + g * 8 + k0), c0);
        c1 = MFMA32(af, ld8(W1T + (32 + cr) * W1P + g * 8 + k0), c1);
        c2 = MFMA32(af, ld8(W1T + (64 + cr) * W1P + g * 8 + k0), c2);
        c3 = MFMA32(af, ld8(W1T + (96 + cr) * W1P + g * 8 + k0), c3);
      }
#pragma unroll
      for (int i = 0; i < 16; ++i) {
        float v = fmaxf(c0[i] + b1v[0], 0.f) * w2v[0]
                + fmaxf(c1[i] + b1v[1], 0.f) * w2v[1]
                + fmaxf(c2[i] + b1v[2], 0.f) * w2v[2]
                + fmaxf(c3[i] + b1v[3], 0.f) * w2v[3];
#pragma unroll
        for (int mm = 1; mm < 32; mm <<= 1) v += __shfl_xor(v, mm);
        if (cr == 0) {
          const int go = m0 + (i & 3) + 8 * (i >> 2) + 4 * g;
          if (go < 400) e2s[go] = v;
        }
      }
    }
  }
  __syncthreads();
  if (tid < Sd) {
    float v0 = e2s[tid * 4], v1 = e2s[tid * 4 + 1];
    float v2 = e2s[tid * 4 + 2], v3 = e2s[tid * 4 + 3];
    const float m = fmaxf(fmaxf(v0, v1), fmaxf(v2, v3));
    v0 = __expf(v0 - m); v1 = __expf(v1 - m);
    v2 = __expf(v2 - m); v3 = __expf(v3 - m);
    const float inv = 1.0f / (v0 + v1 + v2 + v3);
    e2s[tid * 4] = v0 * inv; e2s[tid * 4 + 1] = v1 * inv;
    e2s[tid * 4 + 2] = v2 * inv; e2s[tid * 4 + 3] = v3 * inv;
  }
  __syncthreads();

  // ---------- P6: fuse + scale + mask + row softmax; P in place at ST[q][0..99] ----------
  for (int q = w; q < Sd; q += 8) {
    const float g0v = e2s[q * 4], g1v = e2s[q * 4 + 1];
    const float g2v = e2s[q * 4 + 2], g3v = e2s[q * 4 + 3];
    u16* const sp = ST + q * STP;
    const float* const mp = mask + (size_t)b * 10000 + q * 100;
    float x1 = g0v * bfr(sp[l]) + g1v * bfr(sp[STS + l]) +
               g2v * bfr(sp[2 * STS + l]) + g3v * bfr(sp[3 * STS + l]);
    x1 = x1 * 0.125f + mp[l];
    const bool v2 = (l < 36);
    float x2 = -3e38f;
    if (v2) {
      const int k2 = 64 + l;
      x2 = g0v * bfr(sp[k2]) + g1v * bfr(sp[STS + k2]) +
           g2v * bfr(sp[2 * STS + k2]) + g3v * bfr(sp[3 * STS + k2]);
      x2 = x2 * 0.125f + mp[k2];
    }
    const float M = wmax(fmaxf(x1, x2));
    const float ea = __expf(x1 - M);
    const float eb = v2 ? __expf(x2 - M) : 0.f;
    const float inv = 1.0f / wsum(ea + eb);
    sp[l] = f2bu(ea * inv);
    if (v2) sp[64 + l] = f2bu(eb * inv);
  }
  __syncthreads();

  // ---------- P7: V projection -> VT[c][s], zero-padded k>=100 ----------
  stage_rows4<5>(input + row0 * 128, VA, 100, AP, tid, 512);
  stage_wt<6>(Wv, 128, h * 64, WVT, 128, AP, tid, 512);
  {
    ushort4 z; z.x = z.y = z.z = z.w = 0;
    for (int i = tid; i < 64 * VTP / 4; i += 512)
      *reinterpret_cast<ushort4*>(VT + i * 4) = z;
  }
  __syncthreads();
  for (int u = w; u < 8; u += 8) {
    const int mt = u >> 1, nt = u & 1;
    tile32<128, true>(VA, AP, WVT, AP, bv + h * 64, VT, VTP, 0, mt * 32, nt * 32, l);
  }
  __syncthreads();

  // ---------- P8: PV -> ctx (global f32) ----------
  for (int u = w; u < 8; u += 8) {
    const int mt = u >> 1, nt = u & 1;
    const int m0 = mt * 32, n0 = nt * 32;
    int ar = m0 + cr; if (ar >= Sd) ar = Sd - 1;
    const u16* ap = ST + ar * STP + g * 8;
    const u16* bp = VT + (n0 + cr) * VTP + g * 8;
    f32x16 acc = zf16();
#pragma unroll
    for (int k0 = 0; k0 < 112; k0 += 16)
      acc = MFMA32(ld8(ap + k0), ld8(bp + k0), acc);
#pragma unroll
    for (int i = 0; i < 16; ++i) {
      const int row = m0 + (i & 3) + 8 * (i >> 2) + 4 * g;
      if (row < Sd)
        ctx[(row0 + row) * 128 + h * 64 + n0 + cr] = acc[i];
    }
  }
}

// ---------------------------------------------------------------------------
// Output dense (32x32 MFMA) + bias + residual + LayerNorm, in place over d_out.
// ---------------------------------------------------------------------------
__global__ __launch_bounds__(256) void dense_ln(
    const float* __restrict__ ctxg, const float* __restrict__ Wd,
    const float* __restrict__ bd, const float* __restrict__ resid,
    const float* __restrict__ lng, const float* __restrict__ lnb,
    float* __restrict__ out) {
  __shared__ __align__(16) char L[84480];
  u16* const Ab  = (u16*)L;              // [64][132]
  u16* const WdT = (u16*)(L + 16896);    // [128][132]
  float* const Hs = (float*)(L + 50688); // [64][132] f32
  const int tid = threadIdx.x;
  const size_t row0 = (size_t)blockIdx.x * 64;
  const int l = tid & 63, w = tid >> 6, cr = l & 31, g = l >> 5;

  stage_rows4<5>(ctxg + row0 * 128, Ab, 64, AP, tid, 256);
  for (int idx = tid; idx < 128 * 128; idx += 256) {
    const int c = idx & 127, k = idx >> 7;
    WdT[c * AP + k] = f2bu(Wd[k * 128 + c]);
  }
  __syncthreads();

  for (int u = w; u < 8; u += 4) {
    const int mt = u >> 2, nt = u & 3;
    const int m0 = mt * 32, n0 = nt * 32;
    const u16* ap = Ab + (m0 + cr) * AP + g * 8;
    const u16* bp = WdT + (n0 + cr) * AP + g * 8;
    f32x16 acc = zf16();
#pragma unroll
    for (int k0 = 0; k0 < 128; k0 += 16)
      acc = MFMA32(ld8(ap + k0), ld8(bp + k0), acc);
#pragma unroll
    for (int i = 0; i < 16; ++i) {
      const int row = m0 + (i & 3) + 8 * (i >> 2) + 4 * g;
      Hs[row * AP + n0 + cr] = acc[i];
    }
  }
  __syncthreads();

  for (int rr = w; rr < 64; rr += 4) {
    const size_t grow = row0 + rr;
    const float h1 = Hs[rr * AP + l]      + bd[l]      + resid[grow * 128 + l];
    const float h2 = Hs[rr * AP + 64 + l] + bd[64 + l] + resid[grow * 128 + 64 + l];
    const float mu = wsum(h1 + h2) * (1.0f / 128.0f);
    const float d1 = h1 - mu, d2 = h2 - mu;
    const float var = wsum(d1 * d1 + d2 * d2) * (1.0f / 128.0f);
    const float rs = rsqrtf(var + 1e-12f);
    out[grow * 128 + l]      = d1 * rs * lng[l]      + lnb[l];
    out[grow * 128 + 64 + l] = d2 * rs * lng[64 + l] + lnb[64 + l];
  }
}

}  // namespace

extern "C" void kernel_launch(void* const* d_in, const int* in_sizes, int n_in,
                              void* d_out, int out_size, void* d_ws,
                              size_t ws_size, hipStream_t stream) {
  (void)in_sizes; (void)n_in; (void)out_size; (void)d_ws; (void)ws_size;

  const float* input = (const float*)d_in[0];
  const float* attrT = (const float*)d_in[1];
  const float* posE  = (const float*)d_in[2];
  const float* mask  = (const float*)d_in[3];
  const float* Wq  = (const float*)d_in[4];  const float* bq  = (const float*)d_in[5];
  const float* Wk  = (const float*)d_in[6];  const float* bk  = (const float*)d_in[7];
  const float* Wv  = (const float*)d_in[8];  const float* bv  = (const float*)d_in[9];
  const float* Wqp = (const float*)d_in[10]; const float* bqp = (const float*)d_in[11];
  const float* Wkp = (const float*)d_in[12]; const float* bkp = (const float*)d_in[13];
  const float* Wqa = (const float*)d_in[14]; const float* bqa = (const float*)d_in[15];
  const float* Wka = (const float*)d_in[16]; const float* bka = (const float*)d_in[17];
  const float* W1  = (const float*)d_in[18]; const float* b1  = (const float*)d_in[19];
  const float* W2  = (const float*)d_in[20];
  const float* Wd  = (const float*)d_in[22]; const float* bd  = (const float*)d_in[23];
  const float* lng = (const float*)d_in[24]; const float* lnb = (const float*)d_in[25];

  float* ctx = (float*)d_out;  // d_out doubles as ctx staging, then final output

  attn_mega<<<dim3(B_ * 2), dim3(512), 0, stream>>>(
      input, attrT, posE, mask, Wq, bq, Wk, bk, Wv, bv, Wqp, bqp, Wkp, bkp,
      Wqa, bqa, Wka, bka, W1, b1, W2, ctx);
  dense_ln<<<dim3(BS_ / 64), dim3(256), 0, stream>>>(
      ctx, Wd, bd, input, lng, lnb, ctx);
}

// Round 5
// 413.965 us; speedup vs baseline: 4.8703x; 1.3589x over previous
//
#include <hip/hip_runtime.h>
#include <hip/hip_bf16.h>

using bf16 = __hip_bfloat16;
using u16 = unsigned short;
typedef __attribute__((ext_vector_type(8))) short bf16x8;
typedef __attribute__((ext_vector_type(16))) float f32x16;

namespace {

constexpr int B_  = 1024;
constexpr int Sd  = 100;
constexpr int BS_ = B_ * Sd;

constexpr int NTHR = 1024;   // 16 waves -> 4 waves/SIMD (VGPR 88 < 128, no spill)
constexpr int NW   = 16;

constexpr int STP = 420;   // ST q-row pitch (elems); 210 words % 32 = 18 -> 2-way (free)
constexpr int STS = 104;   // per-stream pitch inside a q-row
constexpr int QKP = 196;   // QC/KC pitch; 98 words % 32 = 2 -> 2-way
constexpr int AP  = 132;   // 128-wide staging pitch; 66 words % 32 = 2
constexpr int ATP = 68;    // 64-wide attr staging pitch; 34 words % 32 = 2
constexpr int W1P = 116;   // W1T pitch; 58 words % 32 = 26 -> 2-way (112 would be 8-way)
constexpr int VTP = 116;

constexpr int O_ST = 0;        // ST [100][420] bf16 = 84,000 B (P1-P3: staging scratch)
constexpr int O_Q  = 84000;    // QC [100][196] = 39,200 (gate: guard+e2s; P7: VA)
constexpr int O_K  = 123200;   // KC [100][196] = 39,200 (gate: W1T; P7/P8: WVT spill + VT)
constexpr int LBYTES = 162400;

__device__ __forceinline__ float bfr(u16 u) {
  unsigned int x = ((unsigned int)u) << 16;
  float f; __builtin_memcpy(&f, &x, 4); return f;
}
__device__ __forceinline__ u16 f2bu(float x) {
  bf16 h = __float2bfloat16(x);
  u16 u; __builtin_memcpy(&u, &h, 2); return u;
}
__device__ __forceinline__ float wsum(float v) {
#pragma unroll
  for (int m = 32; m > 0; m >>= 1) v += __shfl_xor(v, m);
  return v;
}
__device__ __forceinline__ float wmax(float v) {
#pragma unroll
  for (int m = 32; m > 0; m >>= 1) v = fmaxf(v, __shfl_xor(v, m));
  return v;
}

__device__ __forceinline__ f32x16 zf16() {
  f32x16 z;
#pragma unroll
  for (int i = 0; i < 16; ++i) z[i] = 0.f;
  return z;
}
__device__ __forceinline__ f32x16 MFMA32(bf16x8 a, bf16x8 b, f32x16 c) {
  return __builtin_amdgcn_mfma_f32_32x32x16_bf16(a, b, c, 0, 0, 0);
}

// 8 contiguous bf16 at p (8B-aligned) as two b64 reads. Same helper for A and B
// operands -> any k-permutation inside the 16-wide block cancels in the MFMA.
__device__ __forceinline__ bf16x8 ld8(const u16* p) {
  const ushort4 a = *reinterpret_cast<const ushort4*>(p);
  const ushort4 b = *reinterpret_cast<const ushort4*>(p + 4);
  bf16x8 f;
  f[0] = (short)a.x; f[1] = (short)a.y; f[2] = (short)a.z; f[3] = (short)a.w;
  f[4] = (short)b.x; f[5] = (short)b.y; f[6] = (short)b.z; f[7] = (short)b.w;
  return f;
}

// global f32 rows (contiguous, ncol = 4<<L4) -> LDS bf16 [nrow][pitch], float4-vectorized
template <int L4>
__device__ __forceinline__ void stage_rows4(const float* __restrict__ src, u16* dst,
                                            int nrow, int pitch, int tid, int nthr) {
  for (int i = tid; i < (nrow << L4); i += nthr) {
    const int rr = i >> L4, cc = (i & ((1 << L4) - 1)) << 2;
    const float4 v = *reinterpret_cast<const float4*>(src + ((size_t)rr << (L4 + 2)) + cc);
    ushort4 o;
    o.x = f2bu(v.x); o.y = f2bu(v.y); o.z = f2bu(v.z); o.w = f2bu(v.w);
    *reinterpret_cast<ushort4*>(dst + rr * pitch + cc) = o;
  }
}
// W[k][coff+c] -> WT[c][k] bf16 (reads coalesced over c); NC = 1<<LC columns
template <int LC>
__device__ __forceinline__ void stage_wt(const float* __restrict__ W, int ldw, int coff,
                                         u16* dst, int kd, int pitch, int tid, int nthr) {
  constexpr int NC = 1 << LC;
  for (int idx = tid; idx < NC * kd; idx += nthr) {
    const int k = idx >> LC, c = idx & (NC - 1);
    dst[c * pitch + k] = f2bu(W[k * ldw + coff + c]);
  }
}

// One 32x32 output tile: dst = A[100][KD] @ Wt[N][KD]^T + bias.
// TR=false: dst[row][dbase+n0+col]; TR=true: dst[n0+col][dbase+row].
template <int KD, bool TR>
__device__ __forceinline__ void tile32(const u16* A, int apitch, const u16* Wt, int wpitch,
                                       const float* __restrict__ bias, u16* dst, int dpitch,
                                       int dbase, int m0, int n0, int l) {
  const int cr = l & 31, g = l >> 5;
  int ar = m0 + cr; if (ar >= Sd) ar = Sd - 1;
  const u16* ap = A + ar * apitch + g * 8;
  const u16* bp = Wt + (n0 + cr) * wpitch + g * 8;
  f32x16 acc = zf16();
#pragma unroll
  for (int k0 = 0; k0 < KD; k0 += 16)
    acc = MFMA32(ld8(ap + k0), ld8(bp + k0), acc);
  const float bvv = bias[n0 + cr];
#pragma unroll
  for (int i = 0; i < 16; ++i) {
    const int row = m0 + (i & 3) + 8 * (i >> 2) + 4 * g;  // C/D: col=lane&31 (measured)
    if (row < Sd) {
      if (TR) dst[(n0 + cr) * dpitch + dbase + row] = f2bu(acc[i] + bvv);
      else    dst[row * dpitch + dbase + n0 + cr]   = f2bu(acc[i] + bvv);
    }
  }
}

// ---------------------------------------------------------------------------
// Mega-kernel: one block per (b,h), 1024 threads (16 waves), 32x32x16 MFMA.
// ---------------------------------------------------------------------------
__global__ __launch_bounds__(NTHR) void attn_mega(
    const float* __restrict__ input, const float* __restrict__ attrT,
    const float* __restrict__ posE, const float* __restrict__ mask,
    const float* __restrict__ Wq, const float* __restrict__ bq,
    const float* __restrict__ Wk, const float* __restrict__ bk,
    const float* __restrict__ Wv, const float* __restrict__ bv,
    const float* __restrict__ Wqp, const float* __restrict__ bqp,
    const float* __restrict__ Wkp, const float* __restrict__ bkp,
    const float* __restrict__ Wqa, const float* __restrict__ bqa,
    const float* __restrict__ Wka, const float* __restrict__ bka,
    const float* __restrict__ W1, const float* __restrict__ b1,
    const float* __restrict__ W2, float* __restrict__ ctx) {
  __shared__ __align__(16) char L[LBYTES];
  u16* const ST = (u16*)(L + O_ST);            // [100][420]: [q][st*104+k]
  u16* const QC = (u16*)(L + O_Q);             // [100][196]
  u16* const KC = (u16*)(L + O_K);             // [100][196]
  // P1/P2 staging (in ST area)
  u16* const SA  = (u16*)(L + O_ST);           // [100][132]
  u16* const SW1 = (u16*)(L + O_ST + 26400);   // [64][132]
  u16* const SW2 = (u16*)(L + O_ST + 43296);   // [64][132]
  // P3 staging (in ST area)
  u16* const AT0  = (u16*)(L + O_ST);          // [100][68]
  u16* const AT1  = (u16*)(L + O_ST + 13600);
  u16* const WA0Q = (u16*)(L + O_ST + 27200);  // [32][68] x4
  u16* const WA0K = (u16*)(L + O_ST + 31552);
  u16* const WA1Q = (u16*)(L + O_ST + 35904);
  u16* const WA1K = (u16*)(L + O_ST + 40256);
  // gate phase
  float* const e2s = (float*)(L + O_Q + 16);   // [400]; first 16 B of O_Q = zero guard
  u16* const W1T = (u16*)(L + O_K);            // [128][116], zero outside (c<100 && k<100)
  // V phase
  u16* const VA  = (u16*)(L + O_Q);            // [100][132]
  u16* const WVT = (u16*)(L + O_Q + 26400);    // [64][132] (spills 4,096 B into dead W1T)
  u16* const VT  = (u16*)(L + O_K + 8192);     // [64][116], k-cols >=100 zeroed

  const int tid = threadIdx.x;
  const int bh = blockIdx.x;
  const int b = bh >> 1, h = bh & 1;
  const size_t row0 = (size_t)b * Sd;
  const int l = tid & 63, w = tid >> 6;        // w in 0..15
  const int cr = l & 31, g = l >> 5;

  // ---------- P1: Q/K projections ----------
  stage_rows4<5>(input + row0 * 128, SA, 100, AP, tid, NTHR);
  stage_wt<6>(Wq, 128, h * 64, SW1, 128, AP, tid, NTHR);
  stage_wt<6>(Wk, 128, h * 64, SW2, 128, AP, tid, NTHR);
  __syncthreads();
  {
    const int u = w;  // 16 tasks, one per wave
    const int pr = u >> 3, mt = (u >> 1) & 3, nt = u & 1;
    tile32<128, false>(SA, AP, pr ? SW2 : SW1, AP, (pr ? bk : bq) + h * 64,
                       pr ? KC : QC, QKP, 0, mt * 32, nt * 32, l);
  }
  __syncthreads();

  // ---------- P2: QP/KP projections ----------
  stage_rows4<5>(posE + row0 * 128, SA, 100, AP, tid, NTHR);
  stage_wt<6>(Wqp, 128, h * 64, SW1, 128, AP, tid, NTHR);
  stage_wt<6>(Wkp, 128, h * 64, SW2, 128, AP, tid, NTHR);
  __syncthreads();
  {
    const int u = w;
    const int pr = u >> 3, mt = (u >> 1) & 3, nt = u & 1;
    tile32<128, false>(SA, AP, pr ? SW2 : SW1, AP, (pr ? bkp : bqp) + h * 64,
                       pr ? KC : QC, QKP, 64, mt * 32, nt * 32, l);
  }
  __syncthreads();

  // ---------- P3: attribute projections ----------
  stage_rows4<4>(attrT + (size_t)b * 6400, AT0, 100, ATP, tid, NTHR);
  stage_rows4<4>(attrT + (size_t)(B_ + b) * 6400, AT1, 100, ATP, tid, NTHR);
  stage_wt<5>(Wqa, 64, h * 32, WA0Q, 64, ATP, tid, NTHR);
  stage_wt<5>(Wka, 64, h * 32, WA0K, 64, ATP, tid, NTHR);
  stage_wt<5>(Wqa + 4096, 64, h * 32, WA1Q, 64, ATP, tid, NTHR);
  stage_wt<5>(Wka + 4096, 64, h * 32, WA1K, 64, ATP, tid, NTHR);
  __syncthreads();
  {
    const int u = w;
    const int pr = u >> 2, mt = u & 3;  // 0=A0Q 1=A0K 2=A1Q 3=A1K
    const u16* Asrc = (pr < 2) ? AT0 : AT1;
    const u16* Wt = (pr == 0) ? WA0Q : (pr == 1) ? WA0K : (pr == 2) ? WA1Q : WA1K;
    const float* bs = (pr == 0) ? bqa + h * 32 : (pr == 1) ? bka + h * 32
                     : (pr == 2) ? bqa + 64 + h * 32 : bka + 64 + h * 32;
    tile32<64, false>(Asrc, ATP, Wt, ATP, bs, (pr & 1) ? KC : QC, QKP,
                      128 + (pr >> 1) * 32, mt * 32, 0, l);
  }
  __syncthreads();

  // ---------- P4: 4-stream scores -> ST; also finite-fill row pads 416..419 ----------
  {
    ushort4 z; z.x = z.y = z.z = z.w = 0;
    for (int q = tid; q < Sd; q += NTHR)
      *reinterpret_cast<ushort4*>(ST + q * STP + 416) = z;
  }
  {
    const int u = w;  // 16 tile-tasks, one per wave
    const int mt = u >> 2, nt = u & 3;
    const int m0 = mt * 32, n0 = nt * 32;
    int ar = m0 + cr; if (ar >= Sd) ar = Sd - 1;
    int br = n0 + cr; if (br >= Sd) br = Sd - 1;
    const u16* ap = QC + ar * QKP + g * 8;
    const u16* bp = KC + br * QKP + g * 8;
    f32x16 ai = zf16(), po = zf16(), a0 = zf16(), a1 = zf16();
    ai = MFMA32(ld8(ap + 0),   ld8(bp + 0),   ai);
    ai = MFMA32(ld8(ap + 16),  ld8(bp + 16),  ai);
    ai = MFMA32(ld8(ap + 32),  ld8(bp + 32),  ai);
    ai = MFMA32(ld8(ap + 48),  ld8(bp + 48),  ai);
    po = MFMA32(ld8(ap + 64),  ld8(bp + 64),  po);
    po = MFMA32(ld8(ap + 80),  ld8(bp + 80),  po);
    po = MFMA32(ld8(ap + 96),  ld8(bp + 96),  po);
    po = MFMA32(ld8(ap + 112), ld8(bp + 112), po);
    a0 = MFMA32(ld8(ap + 128), ld8(bp + 128), a0);
    a0 = MFMA32(ld8(ap + 144), ld8(bp + 144), a0);
    a1 = MFMA32(ld8(ap + 160), ld8(bp + 160), a1);
    a1 = MFMA32(ld8(ap + 176), ld8(bp + 176), a1);
    const int col = n0 + cr;
    if (col < STS) {  // write pads 100..103 too (finite fill for gate's k-spill)
#pragma unroll
      for (int i = 0; i < 16; ++i) {
        const int row = m0 + (i & 3) + 8 * (i >> 2) + 4 * g;
        if (row < Sd) {
          u16* sp = ST + row * STP + col;
          sp[0]       = f2bu(a0[i]);   // attr0
          sp[STS]     = f2bu(a1[i]);   // attr1
          sp[2 * STS] = f2bu(ai[i]);   // item
          sp[3 * STS] = f2bu(po[i]);   // pos
        }
      }
    }
  }
  __syncthreads();

  // ---------- P5: gate fusion e2 = relu(ST@W1 + b1)@W2, softmax over st ----------
  for (int idx = tid; idx < 128 * 128; idx += NTHR) {
    const int c = idx & 127, k = idx >> 7;
    if (k < W1P)
      W1T[c * W1P + k] = (c < Sd && k < Sd) ? f2bu(W1[k * Sd + c]) : (u16)0;
  }
  if (tid < 8) ((u16*)(L + O_Q))[tid] = 0;  // guard: q=99/st=3 k-spill reads past ST
  __syncthreads();
  {
    float b1v[4], w2v[4];
#pragma unroll
    for (int nt = 0; nt < 4; ++nt) {
      const int c = nt * 32 + cr;
      b1v[nt] = (c < Sd) ? b1[c] : 0.f;
      w2v[nt] = (c < Sd) ? W2[c] : 0.f;
    }
    for (int mt = w; mt < 13; mt += NW) {  // 13 tasks over 16 waves
      const int m0 = mt * 32;
      int gr = m0 + cr; if (gr > 399) gr = 399;
      const u16* ap = ST + (gr >> 2) * STP + (gr & 3) * STS + g * 8;
      f32x16 c0 = zf16(), c1 = zf16(), c2 = zf16(), c3 = zf16();
#pragma unroll
      for (int k0 = 0; k0 < 112; k0 += 16) {
        const bf16x8 af = ld8(ap + k0);
        c0 = MFMA32(af, ld8(W1T + (cr)      * W1P + g * 8 + k0), c0);
        c1 = MFMA32(af, ld8(W1T + (32 + cr) * W1P + g * 8 + k0), c1);
        c2 = MFMA32(af, ld8(W1T + (64 + cr) * W1P + g * 8 + k0), c2);
        c3 = MFMA32(af, ld8(W1T + (96 + cr) * W1P + g * 8 + k0), c3);
      }
#pragma unroll
      for (int i = 0; i < 16; ++i) {
        float v = fmaxf(c0[i] + b1v[0], 0.f) * w2v[0]
                + fmaxf(c1[i] + b1v[1], 0.f) * w2v[1]
                + fmaxf(c2[i] + b1v[2], 0.f) * w2v[2]
                + fmaxf(c3[i] + b1v[3], 0.f) * w2v[3];
#pragma unroll
        for (int mm = 1; mm < 32; mm <<= 1) v += __shfl_xor(v, mm);
        if (cr == 0) {
          const int go = m0 + (i & 3) + 8 * (i >> 2) + 4 * g;
          if (go < 400) e2s[go] = v;
        }
      }
    }
  }
  __syncthreads();
  if (tid < Sd) {
    float v0 = e2s[tid * 4], v1 = e2s[tid * 4 + 1];
    float v2 = e2s[tid * 4 + 2], v3 = e2s[tid * 4 + 3];
    const float m = fmaxf(fmaxf(v0, v1), fmaxf(v2, v3));
    v0 = __expf(v0 - m); v1 = __expf(v1 - m);
    v2 = __expf(v2 - m); v3 = __expf(v3 - m);
    const float inv = 1.0f / (v0 + v1 + v2 + v3);
    e2s[tid * 4] = v0 * inv; e2s[tid * 4 + 1] = v1 * inv;
    e2s[tid * 4 + 2] = v2 * inv; e2s[tid * 4 + 3] = v3 * inv;
  }
  __syncthreads();

  // ---------- P6: fuse + scale + mask + row softmax; P in place at ST[q][0..99] ----------
  for (int q = w; q < Sd; q += NW) {
    const float g0v = e2s[q * 4], g1v = e2s[q * 4 + 1];
    const float g2v = e2s[q * 4 + 2], g3v = e2s[q * 4 + 3];
    u16* const sp = ST + q * STP;
    const float* const mp = mask + (size_t)b * 10000 + q * 100;
    float x1 = g0v * bfr(sp[l]) + g1v * bfr(sp[STS + l]) +
               g2v * bfr(sp[2 * STS + l]) + g3v * bfr(sp[3 * STS + l]);
    x1 = x1 * 0.125f + mp[l];
    const bool v2 = (l < 36);
    float x2 = -3e38f;
    if (v2) {
      const int k2 = 64 + l;
      x2 = g0v * bfr(sp[k2]) + g1v * bfr(sp[STS + k2]) +
           g2v * bfr(sp[2 * STS + k2]) + g3v * bfr(sp[3 * STS + k2]);
      x2 = x2 * 0.125f + mp[k2];
    }
    const float M = wmax(fmaxf(x1, x2));
    const float ea = __expf(x1 - M);
    const float eb = v2 ? __expf(x2 - M) : 0.f;
    const float inv = 1.0f / wsum(ea + eb);
    sp[l] = f2bu(ea * inv);
    if (v2) sp[64 + l] = f2bu(eb * inv);
  }
  __syncthreads();

  // ---------- P7: V projection -> VT[c][s], zero-padded k>=100 ----------
  stage_rows4<5>(input + row0 * 128, VA, 100, AP, tid, NTHR);
  stage_wt<6>(Wv, 128, h * 64, WVT, 128, AP, tid, NTHR);
  {
    ushort4 z; z.x = z.y = z.z = z.w = 0;
    for (int i = tid; i < 64 * VTP / 4; i += NTHR)
      *reinterpret_cast<ushort4*>(VT + i * 4) = z;
  }
  __syncthreads();
  if (w < 8) {
    const int u = w;  // 8 tasks on waves 0..7
    const int mt = u >> 1, nt = u & 1;
    tile32<128, true>(VA, AP, WVT, AP, bv + h * 64, VT, VTP, 0, mt * 32, nt * 32, l);
  }
  __syncthreads();

  // ---------- P8: PV -> ctx (global f32) ----------
  if (w < 8) {
    const int u = w;
    const int mt = u >> 1, nt = u & 1;
    const int m0 = mt * 32, n0 = nt * 32;
    int ar = m0 + cr; if (ar >= Sd) ar = Sd - 1;
    const u16* ap = ST + ar * STP + g * 8;
    const u16* bp = VT + (n0 + cr) * VTP + g * 8;
    f32x16 acc = zf16();
#pragma unroll
    for (int k0 = 0; k0 < 112; k0 += 16)
      acc = MFMA32(ld8(ap + k0), ld8(bp + k0), acc);
#pragma unroll
    for (int i = 0; i < 16; ++i) {
      const int row = m0 + (i & 3) + 8 * (i >> 2) + 4 * g;
      if (row < Sd)
        ctx[(row0 + row) * 128 + h * 64 + n0 + cr] = acc[i];
    }
  }
}

// ---------------------------------------------------------------------------
// Output dense (32x32 MFMA) + bias + residual + LayerNorm, in place over d_out.
// ---------------------------------------------------------------------------
__global__ __launch_bounds__(256) void dense_ln(
    const float* __restrict__ ctxg, const float* __restrict__ Wd,
    const float* __restrict__ bd, const float* __restrict__ resid,
    const float* __restrict__ lng, const float* __restrict__ lnb,
    float* __restrict__ out) {
  __shared__ __align__(16) char L[84480];
  u16* const Ab  = (u16*)L;              // [64][132]
  u16* const WdT = (u16*)(L + 16896);    // [128][132]
  float* const Hs = (float*)(L + 50688); // [64][132] f32
  const int tid = threadIdx.x;
  const size_t row0 = (size_t)blockIdx.x * 64;
  const int l = tid & 63, w = tid >> 6, cr = l & 31, g = l >> 5;

  stage_rows4<5>(ctxg + row0 * 128, Ab, 64, AP, tid, 256);
  for (int idx = tid; idx < 128 * 128; idx += 256) {
    const int c = idx & 127, k = idx >> 7;
    WdT[c * AP + k] = f2bu(Wd[k * 128 + c]);
  }
  __syncthreads();

  for (int u = w; u < 8; u += 4) {
    const int mt = u >> 2, nt = u & 3;
    const int m0 = mt * 32, n0 = nt * 32;
    const u16* ap = Ab + (m0 + cr) * AP + g * 8;
    const u16* bp = WdT + (n0 + cr) * AP + g * 8;
    f32x16 acc = zf16();
#pragma unroll
    for (int k0 = 0; k0 < 128; k0 += 16)
      acc = MFMA32(ld8(ap + k0), ld8(bp + k0), acc);
#pragma unroll
    for (int i = 0; i < 16; ++i) {
      const int row = m0 + (i & 3) + 8 * (i >> 2) + 4 * g;
      Hs[row * AP + n0 + cr] = acc[i];
    }
  }
  __syncthreads();

  for (int rr = w; rr < 64; rr += 4) {
    const size_t grow = row0 + rr;
    const float h1 = Hs[rr * AP + l]      + bd[l]      + resid[grow * 128 + l];
    const float h2 = Hs[rr * AP + 64 + l] + bd[64 + l] + resid[grow * 128 + 64 + l];
    const float mu = wsum(h1 + h2) * (1.0f / 128.0f);
    const float d1 = h1 - mu, d2 = h2 - mu;
    const float var = wsum(d1 * d1 + d2 * d2) * (1.0f / 128.0f);
    const float rs = rsqrtf(var + 1e-12f);
    out[grow * 128 + l]      = d1 * rs * lng[l]      + lnb[l];
    out[grow * 128 + 64 + l] = d2 * rs * lng[64 + l] + lnb[64 + l];
  }
}

}  // namespace

extern "C" void kernel_launch(void* const* d_in, const int* in_sizes, int n_in,
                              void* d_out, int out_size, void* d_ws,
                              size_t ws_size, hipStream_t stream) {
  (void)in_sizes; (void)n_in; (void)out_size; (void)d_ws; (void)ws_size;

  const float* input = (const float*)d_in[0];
  const float* attrT = (const float*)d_in[1];
  const float* posE  = (const float*)d_in[2];
  const float* mask  = (const float*)d_in[3];
  const float* Wq  = (const float*)d_in[4];  const float* bq  = (const float*)d_in[5];
  const float* Wk  = (const float*)d_in[6];  const float* bk  = (const float*)d_in[7];
  const float* Wv  = (const float*)d_in[8];  const float* bv  = (const float*)d_in[9];
  const float* Wqp = (const float*)d_in[10]; const float* bqp = (const float*)d_in[11];
  const float* Wkp = (const float*)d_in[12]; const float* bkp = (const float*)d_in[13];
  const float* Wqa = (const float*)d_in[14]; const float* bqa = (const float*)d_in[15];
  const float* Wka = (const float*)d_in[16]; const float* bka = (const float*)d_in[17];
  const float* W1  = (const float*)d_in[18]; const float* b1  = (const float*)d_in[19];
  const float* W2  = (const float*)d_in[20];
  const float* Wd  = (const float*)d_in[22]; const float* bd  = (const float*)d_in[23];
  const float* lng = (const float*)d_in[24]; const float* lnb = (const float*)d_in[25];

  float* ctx = (float*)d_out;  // d_out doubles as ctx staging, then final output

  attn_mega<<<dim3(B_ * 2), dim3(NTHR), 0, stream>>>(
      input, attrT, posE, mask, Wq, bq, Wk, bk, Wv, bv, Wqp, bqp, Wkp, bkp,
      Wqa, bqa, Wka, bka, W1, b1, W2, ctx);
  dense_ln<<<dim3(BS_ / 64), dim3(256), 0, stream>>>(
      ctx, Wd, bd, input, lng, lnb, ctx);
}

// Round 6
// 325.191 us; speedup vs baseline: 6.1998x; 1.2730x over previous
//
#include <hip/hip_runtime.h>
#include <hip/hip_bf16.h>

using bf16 = __hip_bfloat16;
using u16 = unsigned short;
typedef __attribute__((ext_vector_type(8))) short bf16x8;
typedef __attribute__((ext_vector_type(16))) float f32x16;

namespace {

constexpr int B_  = 1024;
constexpr int Sd  = 100;
constexpr int BS_ = B_ * Sd;

constexpr int NTHR = 1024;   // 16 waves -> 4 waves/SIMD
constexpr int NW   = 16;

constexpr int STP = 420;   // ST q-row pitch; 2-way bank alias (free)
constexpr int STS = 104;   // per-stream pitch inside a q-row
constexpr int QKP = 196;   // QC/KC pitch
constexpr int AP  = 132;   // 128-wide staging pitch
constexpr int ATP = 68;    // 64-wide attr staging pitch
constexpr int W1P = 116;   // W1T pitch (112 would be 8-way conflict)
constexpr int VTP = 116;

constexpr int O_ST = 0;        // ST [100][420] = 84,000 B (P1-P3: staging scratch)
constexpr int O_Q  = 84000;    // QC [100][196] = 39,200 (P6+: VA [100][132])
constexpr int O_K  = 123200;   // KC [100][196] = 39,200 (P5: W1T+e2s; P6+: WVT, VT, e2s)
constexpr int E2S  = 32000;    // e2s f32[400] at O_K+32000 (dead-KC tail; > VT end 31744)
constexpr int LBYTES = 162400;

__device__ __forceinline__ float bfr(u16 u) {
  unsigned int x = ((unsigned int)u) << 16;
  float f; __builtin_memcpy(&f, &x, 4); return f;
}
__device__ __forceinline__ u16 f2bu(float x) {
  bf16 h = __float2bfloat16(x);
  u16 u; __builtin_memcpy(&u, &h, 2); return u;
}
__device__ __forceinline__ float4 ld4(const float* p) {
  return *reinterpret_cast<const float4*>(p);
}
__device__ __forceinline__ float wsum(float v) {
#pragma unroll
  for (int m = 32; m > 0; m >>= 1) v += __shfl_xor(v, m);
  return v;
}
__device__ __forceinline__ float wmax(float v) {
#pragma unroll
  for (int m = 32; m > 0; m >>= 1) v = fmaxf(v, __shfl_xor(v, m));
  return v;
}

__device__ __forceinline__ f32x16 zf16() {
  f32x16 z;
#pragma unroll
  for (int i = 0; i < 16; ++i) z[i] = 0.f;
  return z;
}
__device__ __forceinline__ f32x16 MFMA32(bf16x8 a, bf16x8 b, f32x16 c) {
  return __builtin_amdgcn_mfma_f32_32x32x16_bf16(a, b, c, 0, 0, 0);
}

// 8 contiguous bf16 (8B-aligned) as two b64 reads; same helper for A and B
// operands -> any k-permutation inside the 16-block cancels in the MFMA.
__device__ __forceinline__ bf16x8 ld8(const u16* p) {
  const ushort4 a = *reinterpret_cast<const ushort4*>(p);
  const ushort4 b = *reinterpret_cast<const ushort4*>(p + 4);
  bf16x8 f;
  f[0] = (short)a.x; f[1] = (short)a.y; f[2] = (short)a.z; f[3] = (short)a.w;
  f[4] = (short)b.x; f[5] = (short)b.y; f[6] = (short)b.z; f[7] = (short)b.w;
  return f;
}

// global f32 rows (contiguous, ncol = 4<<L4) -> LDS bf16 [nrow][pitch]
template <int L4>
__device__ __forceinline__ void stage_rows4(const float* __restrict__ src, u16* dst,
                                            int nrow, int pitch, int tid, int nthr) {
  for (int i = tid; i < (nrow << L4); i += nthr) {
    const int rr = i >> L4, cc = (i & ((1 << L4) - 1)) << 2;
    const float4 v = *reinterpret_cast<const float4*>(src + ((size_t)rr << (L4 + 2)) + cc);
    ushort4 o;
    o.x = f2bu(v.x); o.y = f2bu(v.y); o.z = f2bu(v.z); o.w = f2bu(v.w);
    *reinterpret_cast<ushort4*>(dst + rr * pitch + cc) = o;
  }
}
// W[k][coff+c] -> WT[c][k] bf16; NC = 1<<LC columns
template <int LC>
__device__ __forceinline__ void stage_wt(const float* __restrict__ W, int ldw, int coff,
                                         u16* dst, int kd, int pitch, int tid, int nthr) {
  constexpr int NC = 1 << LC;
  for (int idx = tid; idx < NC * kd; idx += nthr) {
    const int k = idx >> LC, c = idx & (NC - 1);
    dst[c * pitch + k] = f2bu(W[k * ldw + coff + c]);
  }
}

// One 32x32 output tile: dst = A[100][KD] @ Wt[N][KD]^T + bias.
// TR=false: dst[row][dbase+n0+col]; TR=true: dst[n0+col][dbase+row].
template <int KD, bool TR>
__device__ __forceinline__ void tile32(const u16* A, int apitch, const u16* Wt, int wpitch,
                                       const float* __restrict__ bias, u16* dst, int dpitch,
                                       int dbase, int m0, int n0, int l) {
  const int cr = l & 31, g = l >> 5;
  int ar = m0 + cr; if (ar >= Sd) ar = Sd - 1;
  const u16* ap = A + ar * apitch + g * 8;
  const u16* bp = Wt + (n0 + cr) * wpitch + g * 8;
  f32x16 acc = zf16();
#pragma unroll
  for (int k0 = 0; k0 < KD; k0 += 16)
    acc = MFMA32(ld8(ap + k0), ld8(bp + k0), acc);
  const float bvv = bias[n0 + cr];
#pragma unroll
  for (int i = 0; i < 16; ++i) {
    const int row = m0 + (i & 3) + 8 * (i >> 2) + 4 * g;  // C/D: col=lane&31 (measured)
    if (row < Sd) {
      if (TR) dst[(n0 + cr) * dpitch + dbase + row] = f2bu(acc[i] + bvv);
      else    dst[row * dpitch + dbase + n0 + cr]   = f2bu(acc[i] + bvv);
    }
  }
}

// ---------------------------------------------------------------------------
// Mega-kernel: one block per (b,h), 1024 threads, T14 cross-phase prefetch.
// ---------------------------------------------------------------------------
__global__ __launch_bounds__(NTHR) void attn_mega(
    const float* __restrict__ input, const float* __restrict__ attrT,
    const float* __restrict__ posE, const float* __restrict__ mask,
    const float* __restrict__ Wq, const float* __restrict__ bq,
    const float* __restrict__ Wk, const float* __restrict__ bk,
    const float* __restrict__ Wv, const float* __restrict__ bv,
    const float* __restrict__ Wqp, const float* __restrict__ bqp,
    const float* __restrict__ Wkp, const float* __restrict__ bkp,
    const float* __restrict__ Wqa, const float* __restrict__ bqa,
    const float* __restrict__ Wka, const float* __restrict__ bka,
    const float* __restrict__ W1, const float* __restrict__ b1,
    const float* __restrict__ W2, float* __restrict__ ctx) {
  __shared__ __align__(16) char L[LBYTES];
  u16* const ST = (u16*)(L + O_ST);            // [100][420]: [q][st*104+k]
  u16* const QC = (u16*)(L + O_Q);             // [100][196]
  u16* const KC = (u16*)(L + O_K);             // [100][196]
  // P1/P2 staging (in ST area)
  u16* const SA  = (u16*)(L + O_ST);           // [100][132]
  u16* const SW1 = (u16*)(L + O_ST + 26400);   // [64][132]
  u16* const SW2 = (u16*)(L + O_ST + 43296);   // [64][132]
  // P3 staging (in ST area)
  u16* const AT0  = (u16*)(L + O_ST);          // [100][68]
  u16* const AT1  = (u16*)(L + O_ST + 13600);
  u16* const WA0Q = (u16*)(L + O_ST + 27200);  // [32][68] x4
  u16* const WA0K = (u16*)(L + O_ST + 31552);
  u16* const WA1Q = (u16*)(L + O_ST + 35904);
  u16* const WA1K = (u16*)(L + O_ST + 40256);
  // gate phase
  u16* const W1T = (u16*)(L + O_K);            // [128][116], zero outside (c<100 && k<100)
  float* const e2s = (float*)(L + O_K + E2S);  // [400] raw gate logits
  // V phase
  u16* const VA  = (u16*)(L + O_Q);            // [100][132] (over dead QC)
  u16* const WVT = (u16*)(L + O_K);            // [64][132] (over dead W1T)
  u16* const VT  = (u16*)(L + O_K + 16896);    // [64][116], ends 31744 < e2s@32000

  const int tid = threadIdx.x;
  const int bh = blockIdx.x;
  const int b = bh >> 1, h = bh & 1;
  const size_t row0 = (size_t)b * Sd;
  const int l = tid & 63, w = tid >> 6;        // w in 0..15
  const int cr = l & 31, g = l >> 5;

  // ---------- S1: stage P1 operands; issue P2 loads (T14) ----------
  stage_rows4<5>(input + row0 * 128, SA, 100, AP, tid, NTHR);
  stage_wt<6>(Wq, 128, h * 64, SW1, 128, AP, tid, NTHR);
  stage_wt<6>(Wk, 128, h * 64, SW2, 128, AP, tid, NTHR);
  float4 r2[8];  // 3200 pos | 2048 Wqp | 2048 Wkp float4s
#pragma unroll
  for (int s = 0; s < 8; ++s) {
    const int fi = tid + s * NTHR;
    if (fi < 3200) {
      r2[s] = ld4(posE + row0 * 128 + fi * 4);
    } else if (fi < 5248) {
      const int f2 = fi - 3200, k = f2 >> 4, c0 = (f2 & 15) << 2;
      r2[s] = ld4(Wqp + k * 128 + h * 64 + c0);
    } else if (fi < 7296) {
      const int f2 = fi - 5248, k = f2 >> 4, c0 = (f2 & 15) << 2;
      r2[s] = ld4(Wkp + k * 128 + h * 64 + c0);
    }
  }
  __syncthreads();

  // ---------- G1: Q/K projections ----------
  {
    const int pr = w >> 3, mt = (w >> 1) & 3, nt = w & 1;
    tile32<128, false>(SA, AP, pr ? SW2 : SW1, AP, (pr ? bk : bq) + h * 64,
                       pr ? KC : QC, QKP, 0, mt * 32, nt * 32, l);
  }
  __syncthreads();

  // ---------- S2: write r2 -> LDS; issue P3 loads ----------
#pragma unroll
  for (int s = 0; s < 8; ++s) {
    const int fi = tid + s * NTHR;
    if (fi < 3200) {
      ushort4 o;
      o.x = f2bu(r2[s].x); o.y = f2bu(r2[s].y); o.z = f2bu(r2[s].z); o.w = f2bu(r2[s].w);
      *reinterpret_cast<ushort4*>(SA + (fi >> 5) * AP + ((fi & 31) << 2)) = o;
    } else if (fi < 5248) {
      const int f2 = fi - 3200, k = f2 >> 4, c0 = (f2 & 15) << 2;
      SW1[c0 * AP + k] = f2bu(r2[s].x); SW1[(c0 + 1) * AP + k] = f2bu(r2[s].y);
      SW1[(c0 + 2) * AP + k] = f2bu(r2[s].z); SW1[(c0 + 3) * AP + k] = f2bu(r2[s].w);
    } else if (fi < 7296) {
      const int f2 = fi - 5248, k = f2 >> 4, c0 = (f2 & 15) << 2;
      SW2[c0 * AP + k] = f2bu(r2[s].x); SW2[(c0 + 1) * AP + k] = f2bu(r2[s].y);
      SW2[(c0 + 2) * AP + k] = f2bu(r2[s].z); SW2[(c0 + 3) * AP + k] = f2bu(r2[s].w);
    }
  }
  float4 r3[6];  // 1600 attr0 | 1600 attr1 | 2048 attrW float4s
#pragma unroll
  for (int s = 0; s < 6; ++s) {
    const int fi = tid + s * NTHR;
    if (fi < 1600) {
      r3[s] = ld4(attrT + (size_t)b * 6400 + fi * 4);
    } else if (fi < 3200) {
      r3[s] = ld4(attrT + (size_t)(B_ + b) * 6400 + (fi - 1600) * 4);
    } else if (fi < 5248) {
      const int f3 = fi - 3200, which = f3 >> 9, fj = f3 & 511;
      const int k = fj >> 3, c0 = (fj & 7) << 2;
      const float* src = (which == 0) ? Wqa : (which == 1) ? Wka
                       : (which == 2) ? (Wqa + 4096) : (Wka + 4096);
      r3[s] = ld4(src + k * 64 + h * 32 + c0);
    }
  }
  __syncthreads();

  // ---------- G2: QP/KP projections ----------
  {
    const int pr = w >> 3, mt = (w >> 1) & 3, nt = w & 1;
    tile32<128, false>(SA, AP, pr ? SW2 : SW1, AP, (pr ? bkp : bqp) + h * 64,
                       pr ? KC : QC, QKP, 64, mt * 32, nt * 32, l);
  }
  __syncthreads();

  // ---------- S3: write r3 -> LDS; issue W1 loads ----------
#pragma unroll
  for (int s = 0; s < 6; ++s) {
    const int fi = tid + s * NTHR;
    if (fi < 1600) {
      ushort4 o;
      o.x = f2bu(r3[s].x); o.y = f2bu(r3[s].y); o.z = f2bu(r3[s].z); o.w = f2bu(r3[s].w);
      *reinterpret_cast<ushort4*>(AT0 + (fi >> 4) * ATP + ((fi & 15) << 2)) = o;
    } else if (fi < 3200) {
      const int f3 = fi - 1600;
      ushort4 o;
      o.x = f2bu(r3[s].x); o.y = f2bu(r3[s].y); o.z = f2bu(r3[s].z); o.w = f2bu(r3[s].w);
      *reinterpret_cast<ushort4*>(AT1 + (f3 >> 4) * ATP + ((f3 & 15) << 2)) = o;
    } else if (fi < 5248) {
      const int f3 = fi - 3200, which = f3 >> 9, fj = f3 & 511;
      const int k = fj >> 3, c0 = (fj & 7) << 2;
      u16* dst = (which == 0) ? WA0Q : (which == 1) ? WA0K
               : (which == 2) ? WA1Q : WA1K;
      dst[c0 * ATP + k] = f2bu(r3[s].x); dst[(c0 + 1) * ATP + k] = f2bu(r3[s].y);
      dst[(c0 + 2) * ATP + k] = f2bu(r3[s].z); dst[(c0 + 3) * ATP + k] = f2bu(r3[s].w);
    }
  }
  float4 r5[3];  // W1: 2500 float4 (held through G3+G4; LDS slot is live KC)
#pragma unroll
  for (int s = 0; s < 3; ++s) {
    const int fi = tid + s * NTHR;
    if (fi < 2500) r5[s] = ld4(W1 + fi * 4);
  }
  __syncthreads();

  // ---------- G3: attribute projections ----------
  {
    const int pr = w >> 2, mt = w & 3;  // 0=A0Q 1=A0K 2=A1Q 3=A1K
    const u16* Asrc = (pr < 2) ? AT0 : AT1;
    const u16* Wt = (pr == 0) ? WA0Q : (pr == 1) ? WA0K : (pr == 2) ? WA1Q : WA1K;
    const float* bs = (pr == 0) ? bqa + h * 32 : (pr == 1) ? bka + h * 32
                     : (pr == 2) ? bqa + 64 + h * 32 : bka + 64 + h * 32;
    tile32<64, false>(Asrc, ATP, Wt, ATP, bs, (pr & 1) ? KC : QC, QKP,
                      128 + (pr >> 1) * 32, mt * 32, 0, l);
  }
  __syncthreads();

  // ---------- G4: 4-stream scores -> ST (+ finite row pads 416..419) ----------
  {
    ushort4 z; z.x = z.y = z.z = z.w = 0;
    for (int q = tid; q < Sd; q += NTHR)
      *reinterpret_cast<ushort4*>(ST + q * STP + 416) = z;
  }
  {
    const int mt = w >> 2, nt = w & 3;
    const int m0 = mt * 32, n0 = nt * 32;
    int ar = m0 + cr; if (ar >= Sd) ar = Sd - 1;
    int br = n0 + cr; if (br >= Sd) br = Sd - 1;
    const u16* ap = QC + ar * QKP + g * 8;
    const u16* bp = KC + br * QKP + g * 8;
    f32x16 ai = zf16(), po = zf16(), a0 = zf16(), a1 = zf16();
    ai = MFMA32(ld8(ap + 0),   ld8(bp + 0),   ai);
    ai = MFMA32(ld8(ap + 16),  ld8(bp + 16),  ai);
    ai = MFMA32(ld8(ap + 32),  ld8(bp + 32),  ai);
    ai = MFMA32(ld8(ap + 48),  ld8(bp + 48),  ai);
    po = MFMA32(ld8(ap + 64),  ld8(bp + 64),  po);
    po = MFMA32(ld8(ap + 80),  ld8(bp + 80),  po);
    po = MFMA32(ld8(ap + 96),  ld8(bp + 96),  po);
    po = MFMA32(ld8(ap + 112), ld8(bp + 112), po);
    a0 = MFMA32(ld8(ap + 128), ld8(bp + 128), a0);
    a0 = MFMA32(ld8(ap + 144), ld8(bp + 144), a0);
    a1 = MFMA32(ld8(ap + 160), ld8(bp + 160), a1);
    a1 = MFMA32(ld8(ap + 176), ld8(bp + 176), a1);
    const int col = n0 + cr;
    if (col < STS) {  // writes pads 100..103 too (finite fill for gate k-spill)
#pragma unroll
      for (int i = 0; i < 16; ++i) {
        const int row = m0 + (i & 3) + 8 * (i >> 2) + 4 * g;
        if (row < Sd) {
          u16* sp = ST + row * STP + col;
          sp[0]       = f2bu(a0[i]);   // attr0
          sp[STS]     = f2bu(a1[i]);   // attr1
          sp[2 * STS] = f2bu(ai[i]);   // item
          sp[3 * STS] = f2bu(po[i]);   // pos
        }
      }
    }
  }
  __syncthreads();

  // ---------- S5: W1T from r5 (zero pads + scatter; disjoint regions) ----------
  {
    ushort4 z; z.x = z.y = z.z = z.w = 0;
    if (tid < 812)  // rows c=100..127: elems 11600..14847
      *reinterpret_cast<ushort4*>(W1T + 11600 + tid * 4) = z;
    if (tid < 400) {  // cols k=100..115 for c<100
      const int c = tid >> 2, kq = 100 + ((tid & 3) << 2);
      *reinterpret_cast<ushort4*>(W1T + c * W1P + kq) = z;
    }
  }
#pragma unroll
  for (int s = 0; s < 3; ++s) {
    const int fi = tid + s * NTHR;
    if (fi < 2500) {
#pragma unroll
      for (int j = 0; j < 4; ++j) {
        const int o = fi * 4 + j;
        const int k = o / 100, c = o - k * 100;
        W1T[c * W1P + k] = f2bu((j == 0) ? r5[s].x : (j == 1) ? r5[s].y
                                : (j == 2) ? r5[s].z : r5[s].w);
      }
    }
  }
  __syncthreads();

  // ---------- G5: gate GEMM -> raw logits e2s ----------
  {
    float b1v[4], w2v[4];
#pragma unroll
    for (int nt = 0; nt < 4; ++nt) {
      const int c = nt * 32 + cr;
      b1v[nt] = (c < Sd) ? b1[c] : 0.f;
      w2v[nt] = (c < Sd) ? W2[c] : 0.f;
    }
    for (int mt = w; mt < 13; mt += NW) {
      const int m0 = mt * 32;
      int gr = m0 + cr; if (gr > 399) gr = 399;
      const u16* ap = ST + (gr >> 2) * STP + (gr & 3) * STS + g * 8;
      f32x16 c0 = zf16(), c1 = zf16(), c2 = zf16(), c3 = zf16();
#pragma unroll
      for (int k0 = 0; k0 < 112; k0 += 16) {
        const bf16x8 af = ld8(ap + k0);
        c0 = MFMA32(af, ld8(W1T + (cr)      * W1P + g * 8 + k0), c0);
        c1 = MFMA32(af, ld8(W1T + (32 + cr) * W1P + g * 8 + k0), c1);
        c2 = MFMA32(af, ld8(W1T + (64 + cr) * W1P + g * 8 + k0), c2);
        c3 = MFMA32(af, ld8(W1T + (96 + cr) * W1P + g * 8 + k0), c3);
      }
#pragma unroll
      for (int i = 0; i < 16; ++i) {
        float v = fmaxf(c0[i] + b1v[0], 0.f) * w2v[0]
                + fmaxf(c1[i] + b1v[1], 0.f) * w2v[1]
                + fmaxf(c2[i] + b1v[2], 0.f) * w2v[2]
                + fmaxf(c3[i] + b1v[3], 0.f) * w2v[3];
#pragma unroll
        for (int mm = 1; mm < 32; mm <<= 1) v += __shfl_xor(v, mm);
        if (cr == 0) {
          const int go = m0 + (i & 3) + 8 * (i >> 2) + 4 * g;
          if (go < 400) e2s[go] = v;
        }
      }
    }
  }
  __syncthreads();

  // ---------- P6: stage V operands + inline gate softmax + fuse/mask/softmax ----------
  stage_rows4<5>(input + row0 * 128, VA, 100, AP, tid, NTHR);
  stage_wt<6>(Wv, 128, h * 64, WVT, 128, AP, tid, NTHR);
  {
    ushort4 z; z.x = z.y = z.z = z.w = 0;
    for (int i2 = tid; i2 < 64 * VTP / 4; i2 += NTHR)
      *reinterpret_cast<ushort4*>(VT + i2 * 4) = z;
  }
  for (int q = w; q < Sd; q += NW) {
    const float* ez = e2s + q * 4;
    float e0 = ez[0], e1 = ez[1], e2v = ez[2], e3 = ez[3];
    const float mg = fmaxf(fmaxf(e0, e1), fmaxf(e2v, e3));
    e0 = __expf(e0 - mg); e1 = __expf(e1 - mg);
    e2v = __expf(e2v - mg); e3 = __expf(e3 - mg);
    const float ginv = 1.0f / (e0 + e1 + e2v + e3);
    const float g0v = e0 * ginv, g1v = e1 * ginv, g2v = e2v * ginv, g3v = e3 * ginv;
    u16* const sp = ST + q * STP;
    const float* const mp = mask + (size_t)b * 10000 + q * 100;
    float x1 = g0v * bfr(sp[l]) + g1v * bfr(sp[STS + l]) +
               g2v * bfr(sp[2 * STS + l]) + g3v * bfr(sp[3 * STS + l]);
    x1 = x1 * 0.125f + mp[l];
    const bool v2 = (l < 36);
    float x2 = -3e38f;
    if (v2) {
      const int k2 = 64 + l;
      x2 = g0v * bfr(sp[k2]) + g1v * bfr(sp[STS + k2]) +
           g2v * bfr(sp[2 * STS + k2]) + g3v * bfr(sp[3 * STS + k2]);
      x2 = x2 * 0.125f + mp[k2];
    }
    const float M = wmax(fmaxf(x1, x2));
    const float ea = __expf(x1 - M);
    const float eb = v2 ? __expf(x2 - M) : 0.f;
    const float inv = 1.0f / wsum(ea + eb);
    sp[l] = f2bu(ea * inv);
    if (v2) sp[64 + l] = f2bu(eb * inv);
  }
  __syncthreads();

  // ---------- G7: V projection -> VT[c][s] ----------
  if (w < 8) {
    const int mt = w >> 1, nt = w & 1;
    tile32<128, true>(VA, AP, WVT, AP, bv + h * 64, VT, VTP, 0, mt * 32, nt * 32, l);
  }
  __syncthreads();

  // ---------- G8: PV -> ctx (global f32) ----------
  if (w < 8) {
    const int mt = w >> 1, nt = w & 1;
    const int m0 = mt * 32, n0 = nt * 32;
    int ar = m0 + cr; if (ar >= Sd) ar = Sd - 1;
    const u16* ap = ST + ar * STP + g * 8;
    const u16* bp = VT + (n0 + cr) * VTP + g * 8;
    f32x16 acc = zf16();
#pragma unroll
    for (int k0 = 0; k0 < 112; k0 += 16)
      acc = MFMA32(ld8(ap + k0), ld8(bp + k0), acc);
#pragma unroll
    for (int i = 0; i < 16; ++i) {
      const int row = m0 + (i & 3) + 8 * (i >> 2) + 4 * g;
      if (row < Sd)
        ctx[(row0 + row) * 128 + h * 64 + n0 + cr] = acc[i];
    }
  }
}

// ---------------------------------------------------------------------------
// Output dense (32x32 MFMA) + bias + residual + LayerNorm, in place over d_out.
// 512 threads, 128 rows/block, bf16 Hs -> 101,376 B LDS, 2 waves/SIMD.
// ---------------------------------------------------------------------------
__global__ __launch_bounds__(512) void dense_ln(
    const float* __restrict__ ctxg, const float* __restrict__ Wd,
    const float* __restrict__ bd, const float* __restrict__ resid,
    const float* __restrict__ lng, const float* __restrict__ lnb,
    float* __restrict__ out) {
  __shared__ __align__(16) char L[101376];
  u16* const Ab  = (u16*)L;              // [128][132]
  u16* const WdT = (u16*)(L + 33792);    // [128][132]
  u16* const Hs  = (u16*)(L + 67584);    // [128][132] bf16 (GEMM term only)
  const int tid = threadIdx.x;
  const size_t row0 = (size_t)blockIdx.x * 128;
  const int l = tid & 63, w = tid >> 6, cr = l & 31, g = l >> 5;

  stage_rows4<5>(ctxg + row0 * 128, Ab, 128, AP, tid, 512);
  stage_wt<7>(Wd, 128, 0, WdT, 128, AP, tid, 512);
  __syncthreads();

  for (int u = w; u < 16; u += 8) {
    const int m0 = (u >> 2) * 32, n0 = (u & 3) * 32;
    const u16* ap = Ab + (m0 + cr) * AP + g * 8;
    const u16* bp = WdT + (n0 + cr) * AP + g * 8;
    f32x16 acc = zf16();
#pragma unroll
    for (int k0 = 0; k0 < 128; k0 += 16)
      acc = MFMA32(ld8(ap + k0), ld8(bp + k0), acc);
#pragma unroll
    for (int i = 0; i < 16; ++i) {
      const int row = m0 + (i & 3) + 8 * (i >> 2) + 4 * g;
      Hs[row * AP + n0 + cr] = f2bu(acc[i]);
    }
  }
  __syncthreads();

  for (int rr = w; rr < 128; rr += 8) {
    const size_t grow = row0 + rr;
    const float h1 = bfr(Hs[rr * AP + l])      + bd[l]      + resid[grow * 128 + l];
    const float h2 = bfr(Hs[rr * AP + 64 + l]) + bd[64 + l] + resid[grow * 128 + 64 + l];
    const float mu = wsum(h1 + h2) * (1.0f / 128.0f);
    const float d1 = h1 - mu, d2 = h2 - mu;
    const float var = wsum(d1 * d1 + d2 * d2) * (1.0f / 128.0f);
    const float rs = rsqrtf(var + 1e-12f);
    out[grow * 128 + l]      = d1 * rs * lng[l]      + lnb[l];
    out[grow * 128 + 64 + l] = d2 * rs * lng[64 + l] + lnb[64 + l];
  }
}

}  // namespace

extern "C" void kernel_launch(void* const* d_in, const int* in_sizes, int n_in,
                              void* d_out, int out_size, void* d_ws,
                              size_t ws_size, hipStream_t stream) {
  (void)in_sizes; (void)n_in; (void)out_size; (void)d_ws; (void)ws_size;

  const float* input = (const float*)d_in[0];
  const float* attrT = (const float*)d_in[1];
  const float* posE  = (const float*)d_in[2];
  const float* mask  = (const float*)d_in[3];
  const float* Wq  = (const float*)d_in[4];  const float* bq  = (const float*)d_in[5];
  const float* Wk  = (const float*)d_in[6];  const float* bk  = (const float*)d_in[7];
  const float* Wv  = (const float*)d_in[8];  const float* bv  = (const float*)d_in[9];
  const float* Wqp = (const float*)d_in[10]; const float* bqp = (const float*)d_in[11];
  const float* Wkp = (const float*)d_in[12]; const float* bkp = (const float*)d_in[13];
  const float* Wqa = (const float*)d_in[14]; const float* bqa = (const float*)d_in[15];
  const float* Wka = (const float*)d_in[16]; const float* bka = (const float*)d_in[17];
  const float* W1  = (const float*)d_in[18]; const float* b1  = (const float*)d_in[19];
  const float* W2  = (const float*)d_in[20];
  const float* Wd  = (const float*)d_in[22]; const float* bd  = (const float*)d_in[23];
  const float* lng = (const float*)d_in[24]; const float* lnb = (const float*)d_in[25];

  float* ctx = (float*)d_out;  // d_out doubles as ctx staging, then final output

  attn_mega<<<dim3(B_ * 2), dim3(NTHR), 0, stream>>>(
      input, attrT, posE, mask, Wq, bq, Wk, bk, Wv, bv, Wqp, bqp, Wkp, bkp,
      Wqa, bqa, Wka, bka, W1, b1, W2, ctx);
  dense_ln<<<dim3(BS_ / 128), dim3(512), 0, stream>>>(
      ctx, Wd, bd, input, lng, lnb, ctx);
}